// Round 1
// baseline (1002.738 us; speedup 1.0000x reference)
//
#include <hip/hip_runtime.h>

// Problem constants (AttentionBlock: B=16, C=256, H=W=32, NH=4, GROUPS=8)
#define NB 16
#define NC 256
#define NS 1024   // H*W
#define NNH 4
#define ND 64     // C/NH
#define NG 8
#define CPG 32    // C/GROUPS
#define GN_EPS 1e-5f

// ---------------------------------------------------------------------------
// Kernel 1: GroupNorm. One block per (b, g). Slab is contiguous: 32*1024 fp32.
// ---------------------------------------------------------------------------
__global__ __launch_bounds__(256) void gn_kernel(
    const float* __restrict__ x, const float* __restrict__ nw,
    const float* __restrict__ nb, float* __restrict__ hn) {
  const int bg = blockIdx.x;
  const int b = bg >> 3, g = bg & 7;
  const size_t base = ((size_t)(b * NC + g * CPG)) * NS;  // 32768 elems
  const float4* xv = (const float4*)(x + base);
  float4* hv = (float4*)(hn + base);
  const int t = threadIdx.x;

  float s1 = 0.f, s2 = 0.f;
  for (int i = t; i < 8192; i += 256) {
    float4 v = xv[i];
    s1 += v.x + v.y + v.z + v.w;
    s2 += v.x * v.x + v.y * v.y + v.z * v.z + v.w * v.w;
  }
  #pragma unroll
  for (int o = 32; o > 0; o >>= 1) {
    s1 += __shfl_down(s1, o, 64);
    s2 += __shfl_down(s2, o, 64);
  }
  __shared__ float rs1[4], rs2[4];
  __shared__ float sh_mean, sh_rstd;
  const int wid = t >> 6, lane = t & 63;
  if (lane == 0) { rs1[wid] = s1; rs2[wid] = s2; }
  __syncthreads();
  if (t == 0) {
    float a = rs1[0] + rs1[1] + rs1[2] + rs1[3];
    float q = rs2[0] + rs2[1] + rs2[2] + rs2[3];
    float mean = a * (1.f / 32768.f);
    float var = q * (1.f / 32768.f) - mean * mean;
    sh_mean = mean;
    sh_rstd = rsqrtf(var + GN_EPS);
  }
  __syncthreads();
  const float mean = sh_mean, rstd = sh_rstd;
  for (int i = t; i < 8192; i += 256) {
    const int c = g * CPG + (i >> 8);   // 256 float4 per channel
    const float wgt = nw[c] * rstd;
    const float bia = nb[c] - mean * wgt;
    float4 v = xv[i];
    float4 o;
    o.x = v.x * wgt + bia;
    o.y = v.y * wgt + bia;
    o.z = v.z * wgt + bia;
    o.w = v.w * wgt + bia;
    hv[i] = o;
  }
}

// ---------------------------------------------------------------------------
// Kernel 2/4: fp32 tiled GEMM:  OUT[b][o][s] = sum_c W[o][c]*IN[b][c][s]+bias
// Tile 64(o) x 64(s), K-step 16, 256 threads, 4x4 acc per thread.
// RES: add X (residual) at epilogue (proj path writes d_out).
// ---------------------------------------------------------------------------
template <int OC, bool RES>
__global__ __launch_bounds__(256) void gemm_kernel(
    const float* __restrict__ W, const float* __restrict__ bias,
    const float* __restrict__ IN, const float* __restrict__ X,
    float* __restrict__ OUT) {
  const int b = blockIdx.z;
  const int o0 = blockIdx.y * 64;
  const int s0 = blockIdx.x * 64;
  __shared__ float Ws[16][72];  // [k][o], padded
  __shared__ float Is[16][72];  // [k][s], padded (72%4==0 so float4 ok)
  const int t = threadIdx.x;
  const int to = t >> 4, ts = t & 15;
  const int wo = t >> 2, wk = (t & 3) * 4;   // W tile: 64 o x 16 k
  const int ik = t >> 4, is = (t & 15) * 4;  // IN tile: 16 k x 64 s
  const float* INb = IN + (size_t)b * NC * NS;
  float acc[4][4] = {};

  for (int k0 = 0; k0 < NC; k0 += 16) {
    const float4 wv = *(const float4*)(W + (size_t)(o0 + wo) * NC + k0 + wk);
    const float4 iv = *(const float4*)(INb + (size_t)(k0 + ik) * NS + s0 + is);
    __syncthreads();  // protect previous iteration's reads
    Ws[wk + 0][wo] = wv.x;
    Ws[wk + 1][wo] = wv.y;
    Ws[wk + 2][wo] = wv.z;
    Ws[wk + 3][wo] = wv.w;
    *(float4*)&Is[ik][is] = iv;
    __syncthreads();
    #pragma unroll
    for (int kk = 0; kk < 16; ++kk) {
      const float4 wr = *(const float4*)&Ws[kk][to * 4];  // broadcast b128
      const float4 ir = *(const float4*)&Is[kk][ts * 4];
      const float wa[4] = {wr.x, wr.y, wr.z, wr.w};
      const float ia[4] = {ir.x, ir.y, ir.z, ir.w};
      #pragma unroll
      for (int i = 0; i < 4; ++i)
        #pragma unroll
        for (int j = 0; j < 4; ++j) acc[i][j] += wa[i] * ia[j];
    }
  }

  const size_t ob = (size_t)b * OC * NS;
  #pragma unroll
  for (int i = 0; i < 4; ++i) {
    const int o = o0 + to * 4 + i;
    const float bi = bias[o];
    const size_t off = ob + (size_t)o * NS + s0 + ts * 4;
    float4 r;
    r.x = acc[i][0] + bi;
    r.y = acc[i][1] + bi;
    r.z = acc[i][2] + bi;
    r.w = acc[i][3] + bi;
    if (RES) {
      const float4 xv = *(const float4*)(X + off);
      r.x += xv.x; r.y += xv.y; r.z += xv.z; r.w += xv.w;
    }
    *(float4*)(OUT + off) = r;
  }
}

// ---------------------------------------------------------------------------
// Kernel 3: flash attention, fp32. One query per thread (256 q / block).
// qkv layout: [B][3*C][S]; q channel = h*64+dd, k = 256+h*64+dd, v = 512+...
// K/V tile (64 keys) staged in LDS as [dd][sk] (natural layout, float4 in/out,
// all compute reads are wave-uniform b128 broadcasts -> conflict-free).
// Online softmax per 16-key chunk; q, O, p all statically indexed registers.
// ---------------------------------------------------------------------------
__global__ __launch_bounds__(256) void attn_kernel(
    const float* __restrict__ qkv, float* __restrict__ att) {
  const int b = blockIdx.z, h = blockIdx.y;
  const int sq = blockIdx.x * 256 + threadIdx.x;
  const float* qb = qkv + ((size_t)b * 3 * NC + h * ND) * NS;
  const float* kb = qb + (size_t)NC * NS;
  const float* vb = qb + (size_t)2 * NC * NS;

  float q[ND], O[ND];
  #pragma unroll
  for (int dd = 0; dd < ND; ++dd) {
    q[dd] = qb[(size_t)dd * NS + sq] * 0.125f;  // fold 1/sqrt(64)
    O[dd] = 0.f;
  }
  float m = -1e30f, l = 0.f;

  __shared__ float Ks[64][64];  // [dd][sk]
  __shared__ float Vs[64][64];

  for (int kt = 0; kt < 16; ++kt) {
    __syncthreads();
    #pragma unroll
    for (int r = 0; r < 4; ++r) {
      const int f = threadIdx.x + 256 * r;   // 1024 float4s for K (and V)
      const int dd = f >> 4, s4 = (f & 15) * 4;
      *(float4*)&Ks[dd][s4] = *(const float4*)(kb + (size_t)dd * NS + kt * 64 + s4);
      *(float4*)&Vs[dd][s4] = *(const float4*)(vb + (size_t)dd * NS + kt * 64 + s4);
    }
    __syncthreads();

    for (int jb = 0; jb < 4; ++jb) {  // 16-key chunks
      const int j0 = jb * 16;
      float p[16];
      #pragma unroll
      for (int j4 = 0; j4 < 4; ++j4) {
        float a0 = 0.f, a1 = 0.f, a2 = 0.f, a3 = 0.f;
        #pragma unroll
        for (int dd = 0; dd < 64; ++dd) {
          const float4 k4 = *(const float4*)&Ks[dd][j0 + j4 * 4];
          const float qq = q[dd];
          a0 += qq * k4.x; a1 += qq * k4.y; a2 += qq * k4.z; a3 += qq * k4.w;
        }
        p[j4 * 4 + 0] = a0; p[j4 * 4 + 1] = a1;
        p[j4 * 4 + 2] = a2; p[j4 * 4 + 3] = a3;
      }
      float mt = p[0];
      #pragma unroll
      for (int j = 1; j < 16; ++j) mt = fmaxf(mt, p[j]);
      const float mn = fmaxf(m, mt);
      const float corr = __expf(m - mn);
      float ls = 0.f;
      #pragma unroll
      for (int j = 0; j < 16; ++j) { p[j] = __expf(p[j] - mn); ls += p[j]; }
      l = l * corr + ls;
      m = mn;
      #pragma unroll
      for (int dd = 0; dd < 64; ++dd) {
        const float4 v0 = *(const float4*)&Vs[dd][j0 + 0];
        const float4 v1 = *(const float4*)&Vs[dd][j0 + 4];
        const float4 v2 = *(const float4*)&Vs[dd][j0 + 8];
        const float4 v3 = *(const float4*)&Vs[dd][j0 + 12];
        O[dd] = O[dd] * corr
              + p[0] * v0.x + p[1] * v0.y + p[2] * v0.z + p[3] * v0.w
              + p[4] * v1.x + p[5] * v1.y + p[6] * v1.z + p[7] * v1.w
              + p[8] * v2.x + p[9] * v2.y + p[10] * v2.z + p[11] * v2.w
              + p[12] * v3.x + p[13] * v3.y + p[14] * v3.z + p[15] * v3.w;
      }
    }
  }

  const float inv = 1.f / l;
  #pragma unroll
  for (int dd = 0; dd < ND; ++dd)
    att[((size_t)b * NC + h * ND + dd) * NS + sq] = O[dd] * inv;
}

// ---------------------------------------------------------------------------
// ws layout (floats): hn [B*C*S] | qkv [B*3C*S] | att [B*C*S]  (80 MiB total)
// ---------------------------------------------------------------------------
extern "C" void kernel_launch(void* const* d_in, const int* in_sizes, int n_in,
                              void* d_out, int out_size, void* d_ws, size_t ws_size,
                              hipStream_t stream) {
  const float* x      = (const float*)d_in[0];
  const float* norm_w = (const float*)d_in[1];
  const float* norm_b = (const float*)d_in[2];
  const float* qkv_w  = (const float*)d_in[3];
  const float* qkv_b  = (const float*)d_in[4];
  const float* proj_w = (const float*)d_in[5];
  const float* proj_b = (const float*)d_in[6];
  float* out = (float*)d_out;

  float* hn   = (float*)d_ws;
  float* qkvb = hn + (size_t)NB * NC * NS;          // +4,194,304
  float* attb = qkvb + (size_t)NB * 3 * NC * NS;    // +12,582,912

  gn_kernel<<<dim3(NB * NG), 256, 0, stream>>>(x, norm_w, norm_b, hn);
  gemm_kernel<768, false><<<dim3(16, 12, NB), 256, 0, stream>>>(
      qkv_w, qkv_b, hn, nullptr, qkvb);
  attn_kernel<<<dim3(4, NNH, NB), 256, 0, stream>>>(qkvb, attb);
  gemm_kernel<256, true><<<dim3(16, 4, NB), 256, 0, stream>>>(
      proj_w, proj_b, attb, x, out);
}

// Round 2
// 196.042 us; speedup vs baseline: 5.1149x; 5.1149x over previous
//
#include <hip/hip_runtime.h>

// AttentionBlock: B=16, C=256, H=W=32, NH=4, GROUPS=8
#define NB 16
#define NC 256
#define NS 1024   // H*W
#define NNH 4
#define ND 64     // C/NH
#define NG 8
#define CPG 32    // C/GROUPS
#define GN_EPS 1e-5f

typedef __attribute__((ext_vector_type(8))) short short8;   // 8 bf16 (4 VGPRs)
typedef __attribute__((ext_vector_type(4))) float f32x4;    // MFMA C/D

static __device__ __forceinline__ ushort f2bf(float x) {
  union { float f; unsigned u; } c; c.f = x;
  unsigned r = (c.u + 0x7fffu + ((c.u >> 16) & 1u)) >> 16;  // RNE
  return (ushort)r;
}

// ---------------------------------------------------------------------------
// Kernel 1: GroupNorm (unchanged from R0). One block per (b,g).
// ---------------------------------------------------------------------------
__global__ __launch_bounds__(256) void gn_kernel(
    const float* __restrict__ x, const float* __restrict__ nw,
    const float* __restrict__ nb, float* __restrict__ hn) {
  const int bg = blockIdx.x;
  const int b = bg >> 3, g = bg & 7;
  const size_t base = ((size_t)(b * NC + g * CPG)) * NS;
  const float4* xv = (const float4*)(x + base);
  float4* hv = (float4*)(hn + base);
  const int t = threadIdx.x;

  float s1 = 0.f, s2 = 0.f;
  for (int i = t; i < 8192; i += 256) {
    float4 v = xv[i];
    s1 += v.x + v.y + v.z + v.w;
    s2 += v.x * v.x + v.y * v.y + v.z * v.z + v.w * v.w;
  }
  #pragma unroll
  for (int o = 32; o > 0; o >>= 1) {
    s1 += __shfl_down(s1, o, 64);
    s2 += __shfl_down(s2, o, 64);
  }
  __shared__ float rs1[4], rs2[4];
  __shared__ float sh_mean, sh_rstd;
  const int wid = t >> 6, lane = t & 63;
  if (lane == 0) { rs1[wid] = s1; rs2[wid] = s2; }
  __syncthreads();
  if (t == 0) {
    float a = rs1[0] + rs1[1] + rs1[2] + rs1[3];
    float q = rs2[0] + rs2[1] + rs2[2] + rs2[3];
    float mean = a * (1.f / 32768.f);
    float var = q * (1.f / 32768.f) - mean * mean;
    sh_mean = mean;
    sh_rstd = rsqrtf(var + GN_EPS);
  }
  __syncthreads();
  const float mean = sh_mean, rstd = sh_rstd;
  for (int i = t; i < 8192; i += 256) {
    const int c = g * CPG + (i >> 8);
    const float wgt = nw[c] * rstd;
    const float bia = nb[c] - mean * wgt;
    float4 v = xv[i];
    float4 o;
    o.x = v.x * wgt + bia;
    o.y = v.y * wgt + bia;
    o.z = v.z * wgt + bia;
    o.w = v.w * wgt + bia;
    hv[i] = o;
  }
}

// ---------------------------------------------------------------------------
// Kernel 2: QKV GEMM (fp32 compute, 64x64 tile) with repacking epilogue:
//   q -> qT [b][h][s][d] bf16 (scaled by 0.125), k -> kT [b][h][s][d] bf16,
//   v -> vN [b][h][d][s] bf16.  o-tile (64) == one (tensor, head) exactly.
// ---------------------------------------------------------------------------
__global__ __launch_bounds__(256) void qkv_gemm_kernel(
    const float* __restrict__ W, const float* __restrict__ bias,
    const float* __restrict__ IN, ushort* __restrict__ qT,
    ushort* __restrict__ kT, ushort* __restrict__ vN) {
  const int b = blockIdx.z;
  const int o0 = blockIdx.y * 64;
  const int s0 = blockIdx.x * 64;
  __shared__ float Ws[16][72];
  __shared__ float Is[16][72];
  const int t = threadIdx.x;
  const int to = t >> 4, ts = t & 15;
  const int wo = t >> 2, wk = (t & 3) * 4;
  const int ik = t >> 4, is = (t & 15) * 4;
  const float* INb = IN + (size_t)b * NC * NS;
  float acc[4][4] = {};

  for (int k0 = 0; k0 < NC; k0 += 16) {
    const float4 wv = *(const float4*)(W + (size_t)(o0 + wo) * NC + k0 + wk);
    const float4 iv = *(const float4*)(INb + (size_t)(k0 + ik) * NS + s0 + is);
    __syncthreads();
    Ws[wk + 0][wo] = wv.x;
    Ws[wk + 1][wo] = wv.y;
    Ws[wk + 2][wo] = wv.z;
    Ws[wk + 3][wo] = wv.w;
    *(float4*)&Is[ik][is] = iv;
    __syncthreads();
    #pragma unroll
    for (int kk = 0; kk < 16; ++kk) {
      const float4 wr = *(const float4*)&Ws[kk][to * 4];
      const float4 ir = *(const float4*)&Is[kk][ts * 4];
      const float wa[4] = {wr.x, wr.y, wr.z, wr.w};
      const float ia[4] = {ir.x, ir.y, ir.z, ir.w};
      #pragma unroll
      for (int i = 0; i < 4; ++i)
        #pragma unroll
        for (int j = 0; j < 4; ++j) acc[i][j] += wa[i] * ia[j];
    }
  }

  const int tsr = o0 >> 8;            // 0=q 1=k 2=v (o-tile aligned to head)
  const int h = (o0 >> 6) & 3;
  const int d0 = (o0 & 63) + to * 4;  // d of acc row i=0
  const float b0 = bias[o0 + to * 4 + 0];
  const float b1 = bias[o0 + to * 4 + 1];
  const float b2 = bias[o0 + to * 4 + 2];
  const float b3 = bias[o0 + to * 4 + 3];
  if (tsr < 2) {
    const float scale = (tsr == 0) ? 0.125f : 1.0f;  // fold 1/sqrt(64) into Q
    ushort* dst = (tsr == 0 ? qT : kT) + ((size_t)(b * 4 + h)) * NS * ND;
    #pragma unroll
    for (int j = 0; j < 4; ++j) {
      ushort4 pk;
      pk.x = f2bf((acc[0][j] + b0) * scale);
      pk.y = f2bf((acc[1][j] + b1) * scale);
      pk.z = f2bf((acc[2][j] + b2) * scale);
      pk.w = f2bf((acc[3][j] + b3) * scale);
      *(ushort4*)(dst + (size_t)(s0 + ts * 4 + j) * ND + d0) = pk;
    }
  } else {
    ushort* dst = vN + ((size_t)(b * 4 + h)) * ND * NS;
    const float bb[4] = {b0, b1, b2, b3};
    #pragma unroll
    for (int i = 0; i < 4; ++i) {
      ushort4 pk;
      pk.x = f2bf(acc[i][0] + bb[i]);
      pk.y = f2bf(acc[i][1] + bb[i]);
      pk.z = f2bf(acc[i][2] + bb[i]);
      pk.w = f2bf(acc[i][3] + bb[i]);
      *(ushort4*)(dst + (size_t)(d0 + i) * NS + s0 + ts * 4) = pk;
    }
  }
}

// ---------------------------------------------------------------------------
// Kernel 3: MFMA flash attention (bf16 inputs, fp32 softmax/acc).
// Block: 256 thr = 4 waves; Q-tile 64 (16 q/wave); K-tile 64.
// LDS rows are 128B -> XOR swizzle byte^=((row&7)<<4) on all tiles (G4).
// QK^T: A=Q[q][d] (qT), B=K^T from Ks[k][d].  PV: A=P[q][k] (per-wave LDS),
// B=V[k][d] from Vs[d][k] (natural layout).  Out: att2[b][s][c] fp32.
// ---------------------------------------------------------------------------
__global__ __launch_bounds__(256) void attn_kernel(
    const ushort* __restrict__ qT, const ushort* __restrict__ kT,
    const ushort* __restrict__ vN, float* __restrict__ att2) {
  __shared__ char smem[32768];
  char* Qs = smem;             // [64 q][64 d] bf16, swizzled
  char* Ks = smem + 8192;      // [64 k][64 d] bf16, swizzled
  char* Vs = smem + 16384;     // [64 d][64 k] bf16, swizzled
  const int b = blockIdx.z, h = blockIdx.y;
  const int sq0 = blockIdx.x * 64;
  const int t = threadIdx.x, w = t >> 6, l = t & 63;
  const int g = l >> 4, li = l & 15;
  char* Ps = smem + 24576 + w * 2048;  // per-wave [16 q][64 k] bf16, swizzled
  const size_t bh = (size_t)(b * 4 + h);
  const ushort* qbase = qT + bh * NS * ND + (size_t)sq0 * ND;
  const ushort* kbase = kT + bh * NS * ND;
  const ushort* vbase = vN + bh * ND * NS;

  // stage Q (coalesced 16B/lane; linear->swizzled LDS)
  #pragma unroll
  for (int i = 0; i < 2; ++i) {
    const int f = t + 256 * i;
    const int row = f >> 3, g8 = f & 7;
    short8 v = *(const short8*)(qbase + (size_t)row * ND + g8 * 8);
    *(short8*)(Qs + ((row * 128 + g8 * 16) ^ ((row & 7) << 4))) = v;
  }
  __syncthreads();
  // hoist Q A-fragments: A[q=w*16+li][d = ks*32 + 8*g + j]
  const short8 aq0 = *(const short8*)(Qs + ((((w * 16 + li) * 128) + g * 16) ^ ((li & 7) << 4)));
  const short8 aq1 = *(const short8*)(Qs + ((((w * 16 + li) * 128) + 64 + g * 16) ^ ((li & 7) << 4)));

  f32x4 acc[4] = {{0.f, 0.f, 0.f, 0.f}, {0.f, 0.f, 0.f, 0.f},
                  {0.f, 0.f, 0.f, 0.f}, {0.f, 0.f, 0.f, 0.f}};
  float mrow[4] = {-1e30f, -1e30f, -1e30f, -1e30f};
  float lrow[4] = {0.f, 0.f, 0.f, 0.f};

  for (int kt = 0; kt < 16; ++kt) {
    __syncthreads();  // protect Ks/Vs reuse from previous iteration's reads
    #pragma unroll
    for (int i = 0; i < 2; ++i) {
      const int f = t + 256 * i;
      const int row = f >> 3, g8 = f & 7;
      const int dst = (row * 128 + g8 * 16) ^ ((row & 7) << 4);
      short8 kv = *(const short8*)(kbase + (size_t)(kt * 64 + row) * ND + g8 * 8);
      *(short8*)(Ks + dst) = kv;
      short8 vv = *(const short8*)(vbase + (size_t)row * NS + kt * 64 + g8 * 8);
      *(short8*)(Vs + dst) = vv;
    }
    __syncthreads();

    // S-tile: 16q x 64k per wave (4 k-subtiles, 2 mfma each over d=64)
    f32x4 sv[4];
    #pragma unroll
    for (int kst = 0; kst < 4; ++kst) {
      const int krow = kst * 16 + li;
      const int swz = (krow & 7) << 4;
      const short8 bk0 = *(const short8*)(Ks + ((krow * 128 + g * 16) ^ swz));
      const short8 bk1 = *(const short8*)(Ks + ((krow * 128 + 64 + g * 16) ^ swz));
      f32x4 sa = {0.f, 0.f, 0.f, 0.f};
      sa = __builtin_amdgcn_mfma_f32_16x16x32_bf16(aq0, bk0, sa, 0, 0, 0);
      sa = __builtin_amdgcn_mfma_f32_16x16x32_bf16(aq1, bk1, sa, 0, 0, 0);
      sv[kst] = sa;
    }

    // online softmax: rows q = w*16 + g*4 + r live on the 16 lanes of group g
    float corr[4];
    #pragma unroll
    for (int r = 0; r < 4; ++r) {
      float mt = fmaxf(fmaxf(sv[0][r], sv[1][r]), fmaxf(sv[2][r], sv[3][r]));
      #pragma unroll
      for (int msk = 1; msk < 16; msk <<= 1)
        mt = fmaxf(mt, __shfl_xor(mt, msk, 64));
      const float mn = fmaxf(mrow[r], mt);
      corr[r] = __expf(mrow[r] - mn);
      mrow[r] = mn;
    }
    float ps[4][4];
    #pragma unroll
    for (int r = 0; r < 4; ++r) {
      float rsum = 0.f;
      #pragma unroll
      for (int kst = 0; kst < 4; ++kst) {
        ps[kst][r] = __expf(sv[kst][r] - mrow[r]);
        rsum += ps[kst][r];
      }
      #pragma unroll
      for (int msk = 1; msk < 16; msk <<= 1) rsum += __shfl_xor(rsum, msk, 64);
      lrow[r] = lrow[r] * corr[r] + rsum;
    }
    // P -> per-wave LDS (bf16), rows q=g*4+r, col k=kst*16+li
    #pragma unroll
    for (int kst = 0; kst < 4; ++kst)
      #pragma unroll
      for (int r = 0; r < 4; ++r) {
        const int q = g * 4 + r;
        *(ushort*)(Ps + ((q * 128 + (kst * 16 + li) * 2) ^ ((q & 7) << 4))) =
            f2bf(ps[kst][r]);
      }
    // rescale accumulator rows
    #pragma unroll
    for (int dt = 0; dt < 4; ++dt)
      #pragma unroll
      for (int r = 0; r < 4; ++r) acc[dt][r] *= corr[r];
    // PV: A = P[q][k], B = V[k][d] read from Vs[d][k]
    #pragma unroll
    for (int ks2 = 0; ks2 < 2; ++ks2) {
      const short8 pa = *(const short8*)(Ps + ((li * 128 + ks2 * 64 + g * 16) ^ ((li & 7) << 4)));
      #pragma unroll
      for (int dt = 0; dt < 4; ++dt) {
        const int vrow = dt * 16 + li;
        const short8 bv = *(const short8*)(Vs + ((vrow * 128 + ks2 * 64 + g * 16) ^ ((vrow & 7) << 4)));
        acc[dt] = __builtin_amdgcn_mfma_f32_16x16x32_bf16(pa, bv, acc[dt], 0, 0, 0);
      }
    }
  }

  // epilogue: out[b][s][c], c = h*64 + dt*16 + li, s = sq0 + w*16 + g*4 + r
  float inv[4];
  #pragma unroll
  for (int r = 0; r < 4; ++r) inv[r] = 1.f / lrow[r];
  float* obase = att2 + ((size_t)b * NS + sq0 + w * 16) * NC + h * 64;
  #pragma unroll
  for (int dt = 0; dt < 4; ++dt)
    #pragma unroll
    for (int r = 0; r < 4; ++r)
      obase[(size_t)(g * 4 + r) * NC + dt * 16 + li] = acc[dt][r] * inv[r];
}

// ---------------------------------------------------------------------------
// Kernel 4: proj GEMM (fp32), IN read from att2[b][s][c]; residual + d_out.
// ---------------------------------------------------------------------------
__global__ __launch_bounds__(256) void proj_gemm_kernel(
    const float* __restrict__ W, const float* __restrict__ bias,
    const float* __restrict__ ATT, const float* __restrict__ X,
    float* __restrict__ OUT) {
  const int b = blockIdx.z;
  const int o0 = blockIdx.y * 64;
  const int s0 = blockIdx.x * 64;
  __shared__ float Ws[16][72];
  __shared__ float Is[16][72];
  const int t = threadIdx.x;
  const int to = t >> 4, ts = t & 15;
  const int wo = t >> 2, wk = (t & 3) * 4;
  const int is_s = t >> 2, ic4 = (t & 3) * 4;  // [s][c] tile load
  const float* ATTb = ATT + (size_t)b * NS * NC;
  float acc[4][4] = {};

  for (int k0 = 0; k0 < NC; k0 += 16) {
    const float4 wv = *(const float4*)(W + (size_t)(o0 + wo) * NC + k0 + wk);
    const float4 iv = *(const float4*)(ATTb + (size_t)(s0 + is_s) * NC + k0 + ic4);
    __syncthreads();
    Ws[wk + 0][wo] = wv.x;
    Ws[wk + 1][wo] = wv.y;
    Ws[wk + 2][wo] = wv.z;
    Ws[wk + 3][wo] = wv.w;
    Is[ic4 + 0][is_s] = iv.x;
    Is[ic4 + 1][is_s] = iv.y;
    Is[ic4 + 2][is_s] = iv.z;
    Is[ic4 + 3][is_s] = iv.w;
    __syncthreads();
    #pragma unroll
    for (int kk = 0; kk < 16; ++kk) {
      const float4 wr = *(const float4*)&Ws[kk][to * 4];
      const float4 ir = *(const float4*)&Is[kk][ts * 4];
      const float wa[4] = {wr.x, wr.y, wr.z, wr.w};
      const float ia[4] = {ir.x, ir.y, ir.z, ir.w};
      #pragma unroll
      for (int i = 0; i < 4; ++i)
        #pragma unroll
        for (int j = 0; j < 4; ++j) acc[i][j] += wa[i] * ia[j];
    }
  }

  const size_t ob = (size_t)b * NC * NS;
  #pragma unroll
  for (int i = 0; i < 4; ++i) {
    const int o = o0 + to * 4 + i;
    const float bi = bias[o];
    const size_t off = ob + (size_t)o * NS + s0 + ts * 4;
    const float4 xv = *(const float4*)(X + off);
    float4 r;
    r.x = acc[i][0] + bi + xv.x;
    r.y = acc[i][1] + bi + xv.y;
    r.z = acc[i][2] + bi + xv.z;
    r.w = acc[i][3] + bi + xv.w;
    *(float4*)(OUT + off) = r;
  }
}

// ---------------------------------------------------------------------------
// ws layout: hn f32[4194304] | att2 f32[4194304] | qT u16[4194304] |
//            kT u16[4194304] | vN u16[4194304]   = 56 MiB
// ---------------------------------------------------------------------------
extern "C" void kernel_launch(void* const* d_in, const int* in_sizes, int n_in,
                              void* d_out, int out_size, void* d_ws, size_t ws_size,
                              hipStream_t stream) {
  const float* x      = (const float*)d_in[0];
  const float* norm_w = (const float*)d_in[1];
  const float* norm_b = (const float*)d_in[2];
  const float* qkv_w  = (const float*)d_in[3];
  const float* qkv_b  = (const float*)d_in[4];
  const float* proj_w = (const float*)d_in[5];
  const float* proj_b = (const float*)d_in[6];
  float* out = (float*)d_out;

  float* hn   = (float*)d_ws;
  float* att2 = hn + (size_t)4194304;
  ushort* qT  = (ushort*)(att2 + (size_t)4194304);
  ushort* kT  = qT + (size_t)4194304;
  ushort* vN  = kT + (size_t)4194304;

  gn_kernel<<<dim3(NB * NG), 256, 0, stream>>>(x, norm_w, norm_b, hn);
  qkv_gemm_kernel<<<dim3(16, 12, NB), 256, 0, stream>>>(
      qkv_w, qkv_b, hn, qT, kT, vN);
  attn_kernel<<<dim3(16, NNH, NB), 256, 0, stream>>>(qT, kT, vN, att2);
  proj_gemm_kernel<<<dim3(16, 4, NB), 256, 0, stream>>>(
      proj_w, proj_b, att2, x, out);
}

// Round 3
// 114.717 us; speedup vs baseline: 8.7409x; 1.7089x over previous
//
#include <hip/hip_runtime.h>

// AttentionBlock: B=16, C=256, H=W=32, NH=4, GROUPS=8
#define NB 16
#define NC 256
#define NS 1024   // H*W
#define NNH 4
#define ND 64     // C/NH
#define GN_EPS 1e-5f

typedef __attribute__((ext_vector_type(8))) short short8;   // 8 bf16 (4 VGPRs)
typedef __attribute__((ext_vector_type(4))) float f32x4;    // MFMA C/D

static __device__ __forceinline__ ushort f2bf(float x) {
  union { float f; unsigned u; } c; c.f = x;
  unsigned r = (c.u + 0x7fffu + ((c.u >> 16) & 1u)) >> 16;  // RNE
  return (ushort)r;
}

// ---------------------------------------------------------------------------
// Kernel 1: GroupNorm -> hnT [b][s][c] bf16 (transposed for MFMA B-operand).
// One block per (b,g): 32 channels x 1024 s. Two passes over x (2nd is L2-hot).
// ---------------------------------------------------------------------------
__global__ __launch_bounds__(256) void gn_kernel(
    const float* __restrict__ x, const float* __restrict__ nw,
    const float* __restrict__ nb, ushort* __restrict__ hnT) {
  const int bg = blockIdx.x;
  const int b = bg >> 3, gg = bg & 7;
  const size_t base = ((size_t)(b * NC + gg * 32)) * NS;  // 32768 floats
  const float4* xv = (const float4*)(x + base);
  const int t = threadIdx.x;

  float s1 = 0.f, s2 = 0.f;
  for (int i = t; i < 8192; i += 256) {
    float4 v = xv[i];
    s1 += v.x + v.y + v.z + v.w;
    s2 += v.x * v.x + v.y * v.y + v.z * v.z + v.w * v.w;
  }
  #pragma unroll
  for (int o = 32; o > 0; o >>= 1) {
    s1 += __shfl_down(s1, o, 64);
    s2 += __shfl_down(s2, o, 64);
  }
  __shared__ float rs1[4], rs2[4];
  __shared__ float sh_mean, sh_rstd;
  const int wid = t >> 6, lane = t & 63;
  if (lane == 0) { rs1[wid] = s1; rs2[wid] = s2; }
  __syncthreads();
  if (t == 0) {
    float a = rs1[0] + rs1[1] + rs1[2] + rs1[3];
    float q = rs2[0] + rs2[1] + rs2[2] + rs2[3];
    float mean = a * (1.f / 32768.f);
    float var = q * (1.f / 32768.f) - mean * mean;
    sh_mean = mean;
    sh_rstd = rsqrtf(var + GN_EPS);
  }
  __syncthreads();
  const float mean = sh_mean, rstd = sh_rstd;

  // pass 2: normalize + transposed bf16 scatter (16B chunks per 8-lane group)
  const int cl = t >> 3;                   // 0..31 channel within group
  const int cg = gg * 32 + cl;             // global channel
  const float wgt = nw[cg] * rstd;
  const float bia = nb[cg] - mean * wgt;
  const float* xrow = x + base + (size_t)cl * NS;
  ushort* dst = hnT + (size_t)b * NS * NC + cg;
  for (int k = 0; k < 32; ++k) {
    const int s = (t & 7) * 4 + k * 32;
    const float4 v = *(const float4*)(xrow + s);
    dst[(size_t)(s + 0) * NC] = f2bf(v.x * wgt + bia);
    dst[(size_t)(s + 1) * NC] = f2bf(v.y * wgt + bia);
    dst[(size_t)(s + 2) * NC] = f2bf(v.z * wgt + bia);
    dst[(size_t)(s + 3) * NC] = f2bf(v.w * wgt + bia);
  }
}

// ---------------------------------------------------------------------------
// Kernel 1b: weight fp32 -> bf16 (qkv_w 768x256 then proj_w 256x256).
// ---------------------------------------------------------------------------
__global__ __launch_bounds__(256) void wconv_kernel(
    const float* __restrict__ qw, const float* __restrict__ pw,
    ushort* __restrict__ wbf) {
  const int i = blockIdx.x * 256 + threadIdx.x;  // 65536 float4s
  const float4 v = (i < 49152) ? *(const float4*)(qw + (size_t)i * 4)
                               : *(const float4*)(pw + (size_t)(i - 49152) * 4);
  ushort4 u;
  u.x = f2bf(v.x); u.y = f2bf(v.y); u.z = f2bf(v.z); u.w = f2bf(v.w);
  *(ushort4*)(wbf + (size_t)i * 4) = u;
}

// ---------------------------------------------------------------------------
// Kernel 2/4: bf16 MFMA GEMM.  D[o][s] = sum_c W[o][c] * DATA[b][s][c].
// Block tile 128o x 128s, K-step 64, 4 waves (each 64x64), swizzled LDS.
// EPI=0: qkv repack epilogue (qT/kT [b][h][s][d] bf16, q*0.125; vN [b][h][d][s]).
// EPI=1: proj epilogue: fp32 + bias + residual -> OUT [b][c][s].
// ---------------------------------------------------------------------------
template <int EPI>
__global__ __launch_bounds__(256) void mfma_gemm_kernel(
    const ushort* __restrict__ Wbf, const float* __restrict__ bias,
    const ushort* __restrict__ DATA, const float* __restrict__ X,
    ushort* __restrict__ qT, ushort* __restrict__ kT, ushort* __restrict__ vN,
    float* __restrict__ OUT) {
  __shared__ char smem[32768];
  char* T1 = smem;          // W-tile   [128 o][64 c] bf16, swizzled 128B rows
  char* T2 = smem + 16384;  // data-tile[128 s][64 c] bf16, swizzled
  const int b = blockIdx.z;
  const int o0 = blockIdx.y * 128, s0 = blockIdx.x * 128;
  const int t = threadIdx.x, w = t >> 6, l = t & 63;
  const int g = l >> 4, li = l & 15;
  const ushort* wrow = Wbf + (size_t)o0 * NC;
  const ushort* drow = DATA + ((size_t)b * NS + s0) * NC;

  f32x4 acc[4][4];
  #pragma unroll
  for (int i = 0; i < 4; ++i)
    #pragma unroll
    for (int j = 0; j < 4; ++j) acc[i][j] = (f32x4){0.f, 0.f, 0.f, 0.f};

  const int oh = (w >> 1) * 64, sh = (w & 1) * 64;  // wave quadrant

  for (int k0 = 0; k0 < NC; k0 += 64) {
    short8 r1[4], r2[4];
    #pragma unroll
    for (int i = 0; i < 4; ++i) {
      const int id = t + 256 * i, row = id >> 3, ce = (id & 7) * 8;  // elems
      r1[i] = *(const short8*)(wrow + (size_t)row * NC + k0 + ce);
      r2[i] = *(const short8*)(drow + (size_t)row * NC + k0 + ce);
    }
    __syncthreads();  // protect previous iteration's fragment reads
    #pragma unroll
    for (int i = 0; i < 4; ++i) {
      const int id = t + 256 * i, row = id >> 3, cb = (id & 7) * 16;  // bytes
      const int dst = row * 128 + (cb ^ ((row & 7) << 4));
      *(short8*)(T1 + dst) = r1[i];
      *(short8*)(T2 + dst) = r2[i];
    }
    __syncthreads();
    #pragma unroll
    for (int kk = 0; kk < 2; ++kk) {
      short8 af[4], bfr[4];
      #pragma unroll
      for (int ms = 0; ms < 4; ++ms) {
        const int row = oh + ms * 16 + li;
        af[ms] = *(const short8*)(T1 + row * 128 +
                                  ((kk * 64 + g * 16) ^ ((row & 7) << 4)));
      }
      #pragma unroll
      for (int ns = 0; ns < 4; ++ns) {
        const int row = sh + ns * 16 + li;
        bfr[ns] = *(const short8*)(T2 + row * 128 +
                                   ((kk * 64 + g * 16) ^ ((row & 7) << 4)));
      }
      #pragma unroll
      for (int ms = 0; ms < 4; ++ms)
        #pragma unroll
        for (int ns = 0; ns < 4; ++ns)
          acc[ms][ns] = __builtin_amdgcn_mfma_f32_16x16x32_bf16(
              af[ms], bfr[ns], acc[ms][ns], 0, 0, 0);
    }
  }

  // ---- epilogue ----  (D row = o = oh+ms*16+g*4+r, col = s = sh+ns*16+li)
  const int ob = o0 + oh;  // wave-uniform output-channel base
  if (EPI == 0) {
    const int tsr = ob >> 8;        // 0=q 1=k 2=v
    const int h = (ob >> 6) & 3;
    if (tsr < 2) {
      const float sc = (tsr == 0) ? 0.125f : 1.0f;
      ushort* dst = (tsr == 0 ? qT : kT) + ((size_t)(b * 4 + h)) * NS * ND;
      #pragma unroll
      for (int ms = 0; ms < 4; ++ms) {
        const float4 bv = *(const float4*)(bias + ob + ms * 16 + g * 4);
        const int d0 = ms * 16 + g * 4;
        #pragma unroll
        for (int ns = 0; ns < 4; ++ns) {
          const int s = s0 + sh + ns * 16 + li;
          ushort4 pk;
          pk.x = f2bf((acc[ms][ns][0] + bv.x) * sc);
          pk.y = f2bf((acc[ms][ns][1] + bv.y) * sc);
          pk.z = f2bf((acc[ms][ns][2] + bv.z) * sc);
          pk.w = f2bf((acc[ms][ns][3] + bv.w) * sc);
          *(ushort4*)(dst + (size_t)s * ND + d0) = pk;
        }
      }
    } else {
      ushort* dst = vN + ((size_t)(b * 4 + h)) * ND * NS;
      #pragma unroll
      for (int ms = 0; ms < 4; ++ms) {
        const float4 bv = *(const float4*)(bias + ob + ms * 16 + g * 4);
        const float bvr[4] = {bv.x, bv.y, bv.z, bv.w};
        #pragma unroll
        for (int r = 0; r < 4; ++r) {
          const int d = ms * 16 + g * 4 + r;
          #pragma unroll
          for (int ns = 0; ns < 4; ++ns) {
            const int s = s0 + sh + ns * 16 + li;
            dst[(size_t)d * NS + s] = f2bf(acc[ms][ns][r] + bvr[r]);
          }
        }
      }
    }
  } else {
    float* outb = OUT + (size_t)b * NC * NS;
    const float* xb = X + (size_t)b * NC * NS;
    #pragma unroll
    for (int ms = 0; ms < 4; ++ms) {
      const float4 bv = *(const float4*)(bias + ob + ms * 16 + g * 4);
      const float bvr[4] = {bv.x, bv.y, bv.z, bv.w};
      #pragma unroll
      for (int r = 0; r < 4; ++r) {
        const int c = ob + ms * 16 + g * 4 + r;
        #pragma unroll
        for (int ns = 0; ns < 4; ++ns) {
          const int s = s0 + sh + ns * 16 + li;
          const size_t a = (size_t)c * NS + s;
          outb[a] = acc[ms][ns][r] + bvr[r] + xb[a];
        }
      }
    }
  }
}

// ---------------------------------------------------------------------------
// Kernel 3: MFMA flash attention (unchanged core; epilogue now bf16 [b][s][c]).
// ---------------------------------------------------------------------------
__global__ __launch_bounds__(256) void attn_kernel(
    const ushort* __restrict__ qT, const ushort* __restrict__ kT,
    const ushort* __restrict__ vN, ushort* __restrict__ att2) {
  __shared__ char smem[32768];
  char* Qs = smem;             // [64 q][64 d] bf16, swizzled
  char* Ks = smem + 8192;      // [64 k][64 d] bf16, swizzled
  char* Vs = smem + 16384;     // [64 d][64 k] bf16, swizzled
  const int b = blockIdx.z, h = blockIdx.y;
  const int sq0 = blockIdx.x * 64;
  const int t = threadIdx.x, w = t >> 6, l = t & 63;
  const int g = l >> 4, li = l & 15;
  char* Ps = smem + 24576 + w * 2048;  // per-wave [16 q][64 k] bf16, swizzled
  const size_t bh = (size_t)(b * 4 + h);
  const ushort* qbase = qT + bh * NS * ND + (size_t)sq0 * ND;
  const ushort* kbase = kT + bh * NS * ND;
  const ushort* vbase = vN + bh * ND * NS;

  #pragma unroll
  for (int i = 0; i < 2; ++i) {
    const int f = t + 256 * i;
    const int row = f >> 3, g8 = f & 7;
    short8 v = *(const short8*)(qbase + (size_t)row * ND + g8 * 8);
    *(short8*)(Qs + ((row * 128 + g8 * 16) ^ ((row & 7) << 4))) = v;
  }
  __syncthreads();
  const short8 aq0 = *(const short8*)(Qs + ((((w * 16 + li) * 128) + g * 16) ^ ((li & 7) << 4)));
  const short8 aq1 = *(const short8*)(Qs + ((((w * 16 + li) * 128) + 64 + g * 16) ^ ((li & 7) << 4)));

  f32x4 acc[4] = {{0.f, 0.f, 0.f, 0.f}, {0.f, 0.f, 0.f, 0.f},
                  {0.f, 0.f, 0.f, 0.f}, {0.f, 0.f, 0.f, 0.f}};
  float mrow[4] = {-1e30f, -1e30f, -1e30f, -1e30f};
  float lrow[4] = {0.f, 0.f, 0.f, 0.f};

  for (int kt = 0; kt < 16; ++kt) {
    __syncthreads();
    #pragma unroll
    for (int i = 0; i < 2; ++i) {
      const int f = t + 256 * i;
      const int row = f >> 3, g8 = f & 7;
      const int dst = (row * 128 + g8 * 16) ^ ((row & 7) << 4);
      short8 kv = *(const short8*)(kbase + (size_t)(kt * 64 + row) * ND + g8 * 8);
      *(short8*)(Ks + dst) = kv;
      short8 vv = *(const short8*)(vbase + (size_t)row * NS + kt * 64 + g8 * 8);
      *(short8*)(Vs + dst) = vv;
    }
    __syncthreads();

    f32x4 sv[4];
    #pragma unroll
    for (int kst = 0; kst < 4; ++kst) {
      const int krow = kst * 16 + li;
      const int swz = (krow & 7) << 4;
      const short8 bk0 = *(const short8*)(Ks + ((krow * 128 + g * 16) ^ swz));
      const short8 bk1 = *(const short8*)(Ks + ((krow * 128 + 64 + g * 16) ^ swz));
      f32x4 sa = {0.f, 0.f, 0.f, 0.f};
      sa = __builtin_amdgcn_mfma_f32_16x16x32_bf16(aq0, bk0, sa, 0, 0, 0);
      sa = __builtin_amdgcn_mfma_f32_16x16x32_bf16(aq1, bk1, sa, 0, 0, 0);
      sv[kst] = sa;
    }

    float corr[4];
    #pragma unroll
    for (int r = 0; r < 4; ++r) {
      float mt = fmaxf(fmaxf(sv[0][r], sv[1][r]), fmaxf(sv[2][r], sv[3][r]));
      #pragma unroll
      for (int msk = 1; msk < 16; msk <<= 1)
        mt = fmaxf(mt, __shfl_xor(mt, msk, 64));
      const float mn = fmaxf(mrow[r], mt);
      corr[r] = __expf(mrow[r] - mn);
      mrow[r] = mn;
    }
    float ps[4][4];
    #pragma unroll
    for (int r = 0; r < 4; ++r) {
      float rsum = 0.f;
      #pragma unroll
      for (int kst = 0; kst < 4; ++kst) {
        ps[kst][r] = __expf(sv[kst][r] - mrow[r]);
        rsum += ps[kst][r];
      }
      #pragma unroll
      for (int msk = 1; msk < 16; msk <<= 1) rsum += __shfl_xor(rsum, msk, 64);
      lrow[r] = lrow[r] * corr[r] + rsum;
    }
    #pragma unroll
    for (int kst = 0; kst < 4; ++kst)
      #pragma unroll
      for (int r = 0; r < 4; ++r) {
        const int q = g * 4 + r;
        *(ushort*)(Ps + ((q * 128 + (kst * 16 + li) * 2) ^ ((q & 7) << 4))) =
            f2bf(ps[kst][r]);
      }
    #pragma unroll
    for (int dt = 0; dt < 4; ++dt)
      #pragma unroll
      for (int r = 0; r < 4; ++r) acc[dt][r] *= corr[r];
    #pragma unroll
    for (int ks2 = 0; ks2 < 2; ++ks2) {
      const short8 pa = *(const short8*)(Ps + ((li * 128 + ks2 * 64 + g * 16) ^ ((li & 7) << 4)));
      #pragma unroll
      for (int dt = 0; dt < 4; ++dt) {
        const int vrow = dt * 16 + li;
        const short8 bv = *(const short8*)(Vs + ((vrow * 128 + ks2 * 64 + g * 16) ^ ((vrow & 7) << 4)));
        acc[dt] = __builtin_amdgcn_mfma_f32_16x16x32_bf16(pa, bv, acc[dt], 0, 0, 0);
      }
    }
  }

  float inv[4];
  #pragma unroll
  for (int r = 0; r < 4; ++r) inv[r] = 1.f / lrow[r];
  ushort* obase = att2 + ((size_t)b * NS + sq0 + w * 16) * NC + h * 64;
  #pragma unroll
  for (int dt = 0; dt < 4; ++dt)
    #pragma unroll
    for (int r = 0; r < 4; ++r)
      obase[(size_t)(g * 4 + r) * NC + dt * 16 + li] = f2bf(acc[dt][r] * inv[r]);
}

// ---------------------------------------------------------------------------
// ws (ushort): hnT[4.19M] qT[4.19M] kT[4.19M] vN[4.19M] att2[4.19M] wbf[262144]
// ---------------------------------------------------------------------------
extern "C" void kernel_launch(void* const* d_in, const int* in_sizes, int n_in,
                              void* d_out, int out_size, void* d_ws, size_t ws_size,
                              hipStream_t stream) {
  const float* x      = (const float*)d_in[0];
  const float* norm_w = (const float*)d_in[1];
  const float* norm_b = (const float*)d_in[2];
  const float* qkv_w  = (const float*)d_in[3];
  const float* qkv_b  = (const float*)d_in[4];
  const float* proj_w = (const float*)d_in[5];
  const float* proj_b = (const float*)d_in[6];
  float* out = (float*)d_out;

  ushort* hnT  = (ushort*)d_ws;
  ushort* qT   = hnT + (size_t)4194304;
  ushort* kT   = qT + (size_t)4194304;
  ushort* vN   = kT + (size_t)4194304;
  ushort* att2 = vN + (size_t)4194304;
  ushort* wbf  = att2 + (size_t)4194304;
  ushort* wq = wbf;
  ushort* wp = wbf + (size_t)196608;

  gn_kernel<<<dim3(128), 256, 0, stream>>>(x, norm_w, norm_b, hnT);
  wconv_kernel<<<dim3(256), 256, 0, stream>>>(qkv_w, proj_w, wbf);
  mfma_gemm_kernel<0><<<dim3(8, 6, NB), 256, 0, stream>>>(
      wq, qkv_b, hnT, nullptr, qT, kT, vN, nullptr);
  attn_kernel<<<dim3(16, NNH, NB), 256, 0, stream>>>(qT, kT, vN, att2);
  mfma_gemm_kernel<1><<<dim3(8, 2, NB), 256, 0, stream>>>(
      wp, proj_b, att2, x, nullptr, nullptr, nullptr, out);
}

// Round 4
// 87.941 us; speedup vs baseline: 11.4024x; 1.3045x over previous
//
#include <hip/hip_runtime.h>

// AttentionBlock: B=16, C=256, H=W=32, NH=4, GROUPS=8
#define NB 16
#define NC 256
#define NS 1024   // H*W
#define NNH 4
#define ND 64     // C/NH
#define GN_EPS 1e-5f

typedef __attribute__((ext_vector_type(8))) short short8;   // 8 bf16 (4 VGPRs)
typedef __attribute__((ext_vector_type(4))) float f32x4;    // MFMA C/D

static __device__ __forceinline__ ushort f2bf(float x) {
  union { float f; unsigned u; } c; c.f = x;
  unsigned r = (c.u + 0x7fffu + ((c.u >> 16) & 1u)) >> 16;  // RNE
  return (ushort)r;
}
static __device__ __forceinline__ ushort f2bf_fast(float x) {
  union { float f; unsigned u; } c; c.f = x;
  return (ushort)((c.u + 0x8000u) >> 16);  // round-nearest, ties away
}

// ---------------------------------------------------------------------------
// Kernel 1: GroupNorm -> hnT [b][s][c] bf16 (transposed for MFMA B-operand).
// ---------------------------------------------------------------------------
__global__ __launch_bounds__(256) void gn_kernel(
    const float* __restrict__ x, const float* __restrict__ nw,
    const float* __restrict__ nb, ushort* __restrict__ hnT) {
  const int bg = blockIdx.x;
  const int b = bg >> 3, gg = bg & 7;
  const size_t base = ((size_t)(b * NC + gg * 32)) * NS;  // 32768 floats
  const float4* xv = (const float4*)(x + base);
  const int t = threadIdx.x;

  float s1 = 0.f, s2 = 0.f;
  for (int i = t; i < 8192; i += 256) {
    float4 v = xv[i];
    s1 += v.x + v.y + v.z + v.w;
    s2 += v.x * v.x + v.y * v.y + v.z * v.z + v.w * v.w;
  }
  #pragma unroll
  for (int o = 32; o > 0; o >>= 1) {
    s1 += __shfl_down(s1, o, 64);
    s2 += __shfl_down(s2, o, 64);
  }
  __shared__ float rs1[4], rs2[4];
  __shared__ float sh_mean, sh_rstd;
  const int wid = t >> 6, lane = t & 63;
  if (lane == 0) { rs1[wid] = s1; rs2[wid] = s2; }
  __syncthreads();
  if (t == 0) {
    float a = rs1[0] + rs1[1] + rs1[2] + rs1[3];
    float q = rs2[0] + rs2[1] + rs2[2] + rs2[3];
    float mean = a * (1.f / 32768.f);
    float var = q * (1.f / 32768.f) - mean * mean;
    sh_mean = mean;
    sh_rstd = rsqrtf(var + GN_EPS);
  }
  __syncthreads();
  const float mean = sh_mean, rstd = sh_rstd;

  const int cl = t >> 3;                   // 0..31 channel within group
  const int cg = gg * 32 + cl;             // global channel
  const float wgt = nw[cg] * rstd;
  const float bia = nb[cg] - mean * wgt;
  const float* xrow = x + base + (size_t)cl * NS;
  ushort* dst = hnT + (size_t)b * NS * NC + cg;
  for (int k = 0; k < 32; ++k) {
    const int s = (t & 7) * 4 + k * 32;
    const float4 v = *(const float4*)(xrow + s);
    dst[(size_t)(s + 0) * NC] = f2bf(v.x * wgt + bia);
    dst[(size_t)(s + 1) * NC] = f2bf(v.y * wgt + bia);
    dst[(size_t)(s + 2) * NC] = f2bf(v.z * wgt + bia);
    dst[(size_t)(s + 3) * NC] = f2bf(v.w * wgt + bia);
  }
}

// ---------------------------------------------------------------------------
// Kernel 1b: weight fp32 -> bf16 (qkv_w 768x256 then proj_w 256x256).
// ---------------------------------------------------------------------------
__global__ __launch_bounds__(256) void wconv_kernel(
    const float* __restrict__ qw, const float* __restrict__ pw,
    ushort* __restrict__ wbf) {
  const int i = blockIdx.x * 256 + threadIdx.x;  // 65536 float4s
  const float4 v = (i < 49152) ? *(const float4*)(qw + (size_t)i * 4)
                               : *(const float4*)(pw + (size_t)(i - 49152) * 4);
  ushort4 u;
  u.x = f2bf(v.x); u.y = f2bf(v.y); u.z = f2bf(v.z); u.w = f2bf(v.w);
  *(ushort4*)(wbf + (size_t)i * 4) = u;
}

// ---------------------------------------------------------------------------
// Kernel 2/4: bf16 MFMA GEMM (unchanged from R2).
// EPI=0: qkv epilogue (qT scaled by 0.125*log2e for exp2 softmax).
// EPI=1: proj epilogue: fp32 + bias + residual -> OUT [b][c][s].
// ---------------------------------------------------------------------------
template <int EPI>
__global__ __launch_bounds__(256) void mfma_gemm_kernel(
    const ushort* __restrict__ Wbf, const float* __restrict__ bias,
    const ushort* __restrict__ DATA, const float* __restrict__ X,
    ushort* __restrict__ qT, ushort* __restrict__ kT, ushort* __restrict__ vN,
    float* __restrict__ OUT) {
  __shared__ char smem[32768];
  char* T1 = smem;          // W-tile   [128 o][64 c] bf16, swizzled 128B rows
  char* T2 = smem + 16384;  // data-tile[128 s][64 c] bf16, swizzled
  const int b = blockIdx.z;
  const int o0 = blockIdx.y * 128, s0 = blockIdx.x * 128;
  const int t = threadIdx.x, w = t >> 6, l = t & 63;
  const int g = l >> 4, li = l & 15;
  const ushort* wrow = Wbf + (size_t)o0 * NC;
  const ushort* drow = DATA + ((size_t)b * NS + s0) * NC;

  f32x4 acc[4][4];
  #pragma unroll
  for (int i = 0; i < 4; ++i)
    #pragma unroll
    for (int j = 0; j < 4; ++j) acc[i][j] = (f32x4){0.f, 0.f, 0.f, 0.f};

  const int oh = (w >> 1) * 64, sh = (w & 1) * 64;  // wave quadrant

  for (int k0 = 0; k0 < NC; k0 += 64) {
    short8 r1[4], r2[4];
    #pragma unroll
    for (int i = 0; i < 4; ++i) {
      const int id = t + 256 * i, row = id >> 3, ce = (id & 7) * 8;
      r1[i] = *(const short8*)(wrow + (size_t)row * NC + k0 + ce);
      r2[i] = *(const short8*)(drow + (size_t)row * NC + k0 + ce);
    }
    __syncthreads();
    #pragma unroll
    for (int i = 0; i < 4; ++i) {
      const int id = t + 256 * i, row = id >> 3, cb = (id & 7) * 16;
      const int dst = row * 128 + (cb ^ ((row & 7) << 4));
      *(short8*)(T1 + dst) = r1[i];
      *(short8*)(T2 + dst) = r2[i];
    }
    __syncthreads();
    __builtin_amdgcn_s_setprio(1);
    #pragma unroll
    for (int kk = 0; kk < 2; ++kk) {
      short8 af[4], bfr[4];
      #pragma unroll
      for (int ms = 0; ms < 4; ++ms) {
        const int row = oh + ms * 16 + li;
        af[ms] = *(const short8*)(T1 + row * 128 +
                                  ((kk * 64 + g * 16) ^ ((row & 7) << 4)));
      }
      #pragma unroll
      for (int ns = 0; ns < 4; ++ns) {
        const int row = sh + ns * 16 + li;
        bfr[ns] = *(const short8*)(T2 + row * 128 +
                                   ((kk * 64 + g * 16) ^ ((row & 7) << 4)));
      }
      #pragma unroll
      for (int ms = 0; ms < 4; ++ms)
        #pragma unroll
        for (int ns = 0; ns < 4; ++ns)
          acc[ms][ns] = __builtin_amdgcn_mfma_f32_16x16x32_bf16(
              af[ms], bfr[ns], acc[ms][ns], 0, 0, 0);
    }
    __builtin_amdgcn_s_setprio(0);
  }

  const int ob = o0 + oh;  // wave-uniform output-channel base
  if (EPI == 0) {
    const int tsr = ob >> 8;        // 0=q 1=k 2=v
    const int h = (ob >> 6) & 3;
    if (tsr < 2) {
      // q scale folds 1/sqrt(64) AND log2(e) so softmax uses exp2 directly
      const float sc = (tsr == 0) ? 0.18033688f : 1.0f;
      ushort* dst = (tsr == 0 ? qT : kT) + ((size_t)(b * 4 + h)) * NS * ND;
      #pragma unroll
      for (int ms = 0; ms < 4; ++ms) {
        const float4 bv = *(const float4*)(bias + ob + ms * 16 + g * 4);
        const int d0 = ms * 16 + g * 4;
        #pragma unroll
        for (int ns = 0; ns < 4; ++ns) {
          const int s = s0 + sh + ns * 16 + li;
          ushort4 pk;
          pk.x = f2bf((acc[ms][ns][0] + bv.x) * sc);
          pk.y = f2bf((acc[ms][ns][1] + bv.y) * sc);
          pk.z = f2bf((acc[ms][ns][2] + bv.z) * sc);
          pk.w = f2bf((acc[ms][ns][3] + bv.w) * sc);
          *(ushort4*)(dst + (size_t)s * ND + d0) = pk;
        }
      }
    } else {
      ushort* dst = vN + ((size_t)(b * 4 + h)) * ND * NS;
      #pragma unroll
      for (int ms = 0; ms < 4; ++ms) {
        const float4 bv = *(const float4*)(bias + ob + ms * 16 + g * 4);
        const float bvr[4] = {bv.x, bv.y, bv.z, bv.w};
        #pragma unroll
        for (int r = 0; r < 4; ++r) {
          const int d = ms * 16 + g * 4 + r;
          #pragma unroll
          for (int ns = 0; ns < 4; ++ns) {
            const int s = s0 + sh + ns * 16 + li;
            dst[(size_t)d * NS + s] = f2bf(acc[ms][ns][r] + bvr[r]);
          }
        }
      }
    }
  } else {
    float* outb = OUT + (size_t)b * NC * NS;
    const float* xb = X + (size_t)b * NC * NS;
    #pragma unroll
    for (int ms = 0; ms < 4; ++ms) {
      const float4 bv = *(const float4*)(bias + ob + ms * 16 + g * 4);
      const float bvr[4] = {bv.x, bv.y, bv.z, bv.w};
      #pragma unroll
      for (int r = 0; r < 4; ++r) {
        const int c = ob + ms * 16 + g * 4 + r;
        #pragma unroll
        for (int ns = 0; ns < 4; ++ns) {
          const int s = s0 + sh + ns * 16 + li;
          const size_t a = (size_t)c * NS + s;
          outb[a] = acc[ms][ns][r] + bvr[r] + xb[a];
        }
      }
    }
  }
}

// ---------------------------------------------------------------------------
// Kernel 3: MFMA flash attention v3.
//  - QBLK=128 (32 q/wave), KVBLK=64, fixed-max softmax (P=exp2(S), no
//    rescale/corr, l-reduce deferred to end), K/V double-buffered with
//    async-STAGE split (loads issued before compute, LDS writes after).
//  - LDS: KV dbuf 2x16KB + Ps 16KB = 48KB -> 3 blocks/CU cap (grid needs 2).
// ---------------------------------------------------------------------------
__global__ __launch_bounds__(256, 2) void attn_kernel(
    const ushort* __restrict__ qT, const ushort* __restrict__ kT,
    const ushort* __restrict__ vN, ushort* __restrict__ att2) {
  __shared__ char smem[49152];
  const int b = blockIdx.z, h = blockIdx.y;
  const int sq0 = blockIdx.x * 128;
  const int t = threadIdx.x, w = t >> 6, l = t & 63;
  const int g = l >> 4, li = l & 15;
  char* Ps = smem + 32768 + w * 4096;  // per-wave [32 q][64 k] bf16, swizzled
  const size_t bh = (size_t)(b * 4 + h);
  const ushort* qbase = qT + bh * NS * ND + (size_t)sq0 * ND;
  const ushort* kbase = kT + bh * NS * ND;
  const ushort* vbase = vN + bh * ND * NS;

  // ---- stage Q (128 rows x 64 d) into the Ps region, hoist A-fragments ----
  #pragma unroll
  for (int i = 0; i < 4; ++i) {
    const int f = t + 256 * i;       // 0..1023 short8 chunks
    const int row = f >> 3, c8 = f & 7;
    short8 v = *(const short8*)(qbase + (size_t)row * ND + c8 * 8);
    *(short8*)(smem + 32768 + ((row * 128 + c8 * 16) ^ ((row & 7) << 4))) = v;
  }
  __syncthreads();
  short8 aq[2][2];
  #pragma unroll
  for (int m = 0; m < 2; ++m)
    #pragma unroll
    for (int kc = 0; kc < 2; ++kc) {
      const int row = w * 32 + m * 16 + li;
      aq[m][kc] = *(const short8*)(smem + 32768 +
          ((row * 128 + kc * 64 + g * 16) ^ ((row & 7) << 4)));
    }
  // (Ps region is re-used for P during the loop; the first loop barrier
  //  orders these reads before any P write.)

  // ---- prologue: stage K/V tile 0 into buf0 ----
  const int srow = t >> 3, sc8 = t & 7;          // per thread: 2 short8/tile
  const int srow2 = (t + 256) >> 3, sc82 = (t + 256) & 7;
  {
    short8 k0a = *(const short8*)(kbase + (size_t)srow * ND + sc8 * 8);
    short8 k0b = *(const short8*)(kbase + (size_t)srow2 * ND + sc82 * 8);
    short8 v0a = *(const short8*)(vbase + (size_t)srow * NS + sc8 * 8);
    short8 v0b = *(const short8*)(vbase + (size_t)srow2 * NS + sc82 * 8);
    const int d1 = srow * 128 + ((sc8 * 16) ^ ((srow & 7) << 4));
    const int d2 = srow2 * 128 + ((sc82 * 16) ^ ((srow2 & 7) << 4));
    *(short8*)(smem + d1) = k0a;
    *(short8*)(smem + d2) = k0b;
    *(short8*)(smem + 8192 + d1) = v0a;
    *(short8*)(smem + 8192 + d2) = v0b;
  }

  f32x4 acc[2][4];
  #pragma unroll
  for (int m = 0; m < 2; ++m)
    #pragma unroll
    for (int dt = 0; dt < 4; ++dt) acc[m][dt] = (f32x4){0.f, 0.f, 0.f, 0.f};
  float lsum[2][4] = {};

  for (int kt = 0; kt < 16; ++kt) {
    __syncthreads();   // buf[kt&1] staged; previous tile's reads complete
    char* Kc = smem + (kt & 1) * 16384;
    char* Vc = Kc + 8192;

    // issue next tile's global loads (latency hidden under compute)
    short8 nk0, nk1, nv0, nv1;
    if (kt < 15) {
      const ushort* kb = kbase + (size_t)(kt + 1) * 64 * ND;
      const ushort* vb = vbase + (size_t)(kt + 1) * 64;
      nk0 = *(const short8*)(kb + (size_t)srow * ND + sc8 * 8);
      nk1 = *(const short8*)(kb + (size_t)srow2 * ND + sc82 * 8);
      nv0 = *(const short8*)(vb + (size_t)srow * NS + sc8 * 8);
      nv1 = *(const short8*)(vb + (size_t)srow2 * NS + sc82 * 8);
    }

    // ---- QK^T: 32q x 64k per wave ----
    f32x4 sv[2][4];
    __builtin_amdgcn_s_setprio(1);
    #pragma unroll
    for (int kst = 0; kst < 4; ++kst) {
      const int krow = kst * 16 + li;
      const int swz = (krow & 7) << 4;
      const short8 bk0 = *(const short8*)(Kc + ((krow * 128 + g * 16) ^ swz));
      const short8 bk1 = *(const short8*)(Kc + ((krow * 128 + 64 + g * 16) ^ swz));
      #pragma unroll
      for (int m = 0; m < 2; ++m) {
        f32x4 sa = {0.f, 0.f, 0.f, 0.f};
        sa = __builtin_amdgcn_mfma_f32_16x16x32_bf16(aq[m][0], bk0, sa, 0, 0, 0);
        sa = __builtin_amdgcn_mfma_f32_16x16x32_bf16(aq[m][1], bk1, sa, 0, 0, 0);
        sv[m][kst] = sa;
      }
    }
    __builtin_amdgcn_s_setprio(0);

    // ---- softmax: P = exp2(S) (scale pre-folded), partial l in-lane ----
    #pragma unroll
    for (int m = 0; m < 2; ++m)
      #pragma unroll
      for (int kst = 0; kst < 4; ++kst) {
        float p0 = __builtin_amdgcn_exp2f(sv[m][kst][0]);
        float p1 = __builtin_amdgcn_exp2f(sv[m][kst][1]);
        float p2 = __builtin_amdgcn_exp2f(sv[m][kst][2]);
        float p3 = __builtin_amdgcn_exp2f(sv[m][kst][3]);
        lsum[m][0] += p0; lsum[m][1] += p1;
        lsum[m][2] += p2; lsum[m][3] += p3;
        const int kcol = (kst * 16 + li) * 2;
        const int q0 = m * 16 + g * 4;
        *(ushort*)(Ps + ((q0 + 0) * 128 + (kcol ^ (((q0 + 0) & 7) << 4)))) = f2bf_fast(p0);
        *(ushort*)(Ps + ((q0 + 1) * 128 + (kcol ^ (((q0 + 1) & 7) << 4)))) = f2bf_fast(p1);
        *(ushort*)(Ps + ((q0 + 2) * 128 + (kcol ^ (((q0 + 2) & 7) << 4)))) = f2bf_fast(p2);
        *(ushort*)(Ps + ((q0 + 3) * 128 + (kcol ^ (((q0 + 3) & 7) << 4)))) = f2bf_fast(p3);
      }

    // ---- PV: acc[m][dt] += P[32q x 64k] * V[64k x 64d] ----
    __builtin_amdgcn_s_setprio(1);
    #pragma unroll
    for (int ks2 = 0; ks2 < 2; ++ks2) {
      short8 pa[2];
      #pragma unroll
      for (int m = 0; m < 2; ++m) {
        const int prow = m * 16 + li;
        pa[m] = *(const short8*)(Ps + (prow * 128 +
                 ((ks2 * 64 + g * 16) ^ ((li & 7) << 4))));
      }
      #pragma unroll
      for (int dt = 0; dt < 4; ++dt) {
        const int vrow = dt * 16 + li;
        const short8 bv = *(const short8*)(Vc + ((vrow * 128 + ks2 * 64 + g * 16)
                                                 ^ ((vrow & 7) << 4)));
        #pragma unroll
        for (int m = 0; m < 2; ++m)
          acc[m][dt] = __builtin_amdgcn_mfma_f32_16x16x32_bf16(
              pa[m], bv, acc[m][dt], 0, 0, 0);
      }
    }
    __builtin_amdgcn_s_setprio(0);

    // ---- write next tile to the other buffer ----
    if (kt < 15) {
      char* Kn = smem + ((kt + 1) & 1) * 16384;
      char* Vn = Kn + 8192;
      const int d1 = srow * 128 + ((sc8 * 16) ^ ((srow & 7) << 4));
      const int d2 = srow2 * 128 + ((sc82 * 16) ^ ((srow2 & 7) << 4));
      *(short8*)(Kn + d1) = nk0;
      *(short8*)(Kn + d2) = nk1;
      *(short8*)(Vn + d1) = nv0;
      *(short8*)(Vn + d2) = nv1;
    }
  }

  // ---- final l reduction (over the 16 li lanes) and output ----
  float linv[2][4];
  #pragma unroll
  for (int m = 0; m < 2; ++m)
    #pragma unroll
    for (int r = 0; r < 4; ++r) {
      float s = lsum[m][r];
      #pragma unroll
      for (int msk = 1; msk < 16; msk <<= 1) s += __shfl_xor(s, msk, 64);
      linv[m][r] = 1.f / s;
    }
  ushort* obase = att2 + ((size_t)b * NS + sq0 + w * 32) * NC + h * 64;
  #pragma unroll
  for (int m = 0; m < 2; ++m)
    #pragma unroll
    for (int dt = 0; dt < 4; ++dt)
      #pragma unroll
      for (int r = 0; r < 4; ++r)
        obase[(size_t)(m * 16 + g * 4 + r) * NC + dt * 16 + li] =
            f2bf(acc[m][dt][r] * linv[m][r]);
}

// ---------------------------------------------------------------------------
// ws (ushort): hnT[4.19M] qT[4.19M] kT[4.19M] vN[4.19M] att2[4.19M] wbf[262144]
// ---------------------------------------------------------------------------
extern "C" void kernel_launch(void* const* d_in, const int* in_sizes, int n_in,
                              void* d_out, int out_size, void* d_ws, size_t ws_size,
                              hipStream_t stream) {
  const float* x      = (const float*)d_in[0];
  const float* norm_w = (const float*)d_in[1];
  const float* norm_b = (const float*)d_in[2];
  const float* qkv_w  = (const float*)d_in[3];
  const float* qkv_b  = (const float*)d_in[4];
  const float* proj_w = (const float*)d_in[5];
  const float* proj_b = (const float*)d_in[6];
  float* out = (float*)d_out;

  ushort* hnT  = (ushort*)d_ws;
  ushort* qT   = hnT + (size_t)4194304;
  ushort* kT   = qT + (size_t)4194304;
  ushort* vN   = kT + (size_t)4194304;
  ushort* att2 = vN + (size_t)4194304;
  ushort* wbf  = att2 + (size_t)4194304;
  ushort* wq = wbf;
  ushort* wp = wbf + (size_t)196608;

  gn_kernel<<<dim3(128), 256, 0, stream>>>(x, norm_w, norm_b, hnT);
  wconv_kernel<<<dim3(256), 256, 0, stream>>>(qkv_w, proj_w, wbf);
  mfma_gemm_kernel<0><<<dim3(8, 6, NB), 256, 0, stream>>>(
      wq, qkv_b, hnT, nullptr, qT, kT, vN, nullptr);
  attn_kernel<<<dim3(8, NNH, NB), 256, 0, stream>>>(qT, kT, vN, att2);
  mfma_gemm_kernel<1><<<dim3(8, 2, NB), 256, 0, stream>>>(
      wp, proj_b, att2, x, nullptr, nullptr, nullptr, out);
}

// Round 5
// 83.232 us; speedup vs baseline: 12.0474x; 1.0566x over previous
//
#include <hip/hip_runtime.h>

// AttentionBlock: B=16, C=256, H=W=32, NH=4, GROUPS=8
#define NB 16
#define NC 256
#define NS 1024   // H*W
#define NNH 4
#define ND 64     // C/NH
#define GN_EPS 1e-5f

typedef __attribute__((ext_vector_type(8))) short short8;   // 8 bf16 (4 VGPRs)
typedef __attribute__((ext_vector_type(4))) float f32x4;    // MFMA C/D

static __device__ __forceinline__ ushort f2bf(float x) {
  union { float f; unsigned u; } c; c.f = x;
  unsigned r = (c.u + 0x7fffu + ((c.u >> 16) & 1u)) >> 16;  // RNE
  return (ushort)r;
}
static __device__ __forceinline__ ushort f2bf_fast(float x) {
  union { float f; unsigned u; } c; c.f = x;
  return (ushort)((c.u + 0x8000u) >> 16);  // round-nearest, ties away
}

// ---------------------------------------------------------------------------
// Kernel 1: fused GroupNorm (blocks 0..127) + weight bf16 convert (128..383).
// GN: one block per (b,g) -> hnT [b][s][c] bf16.
// ---------------------------------------------------------------------------
__global__ __launch_bounds__(256) void gn_wconv_kernel(
    const float* __restrict__ x, const float* __restrict__ nw,
    const float* __restrict__ nb, ushort* __restrict__ hnT,
    const float* __restrict__ qw, const float* __restrict__ pw,
    ushort* __restrict__ wbf) {
  const int bid = blockIdx.x;
  const int t = threadIdx.x;
  if (bid >= 128) {  // ---- weight convert: 65536 float4s over 256 blocks ----
    const int i = (bid - 128) * 256 + t;
    const float4 v = (i < 49152) ? *(const float4*)(qw + (size_t)i * 4)
                                 : *(const float4*)(pw + (size_t)(i - 49152) * 4);
    ushort4 u;
    u.x = f2bf(v.x); u.y = f2bf(v.y); u.z = f2bf(v.z); u.w = f2bf(v.w);
    *(ushort4*)(wbf + (size_t)i * 4) = u;
    return;
  }
  const int b = bid >> 3, gg = bid & 7;
  const size_t base = ((size_t)(b * NC + gg * 32)) * NS;  // 32768 floats
  const float4* xv = (const float4*)(x + base);

  float s1 = 0.f, s2 = 0.f;
  for (int i = t; i < 8192; i += 256) {
    float4 v = xv[i];
    s1 += v.x + v.y + v.z + v.w;
    s2 += v.x * v.x + v.y * v.y + v.z * v.z + v.w * v.w;
  }
  #pragma unroll
  for (int o = 32; o > 0; o >>= 1) {
    s1 += __shfl_down(s1, o, 64);
    s2 += __shfl_down(s2, o, 64);
  }
  __shared__ float rs1[4], rs2[4];
  __shared__ float sh_mean, sh_rstd;
  const int wid = t >> 6, lane = t & 63;
  if (lane == 0) { rs1[wid] = s1; rs2[wid] = s2; }
  __syncthreads();
  if (t == 0) {
    float a = rs1[0] + rs1[1] + rs1[2] + rs1[3];
    float q = rs2[0] + rs2[1] + rs2[2] + rs2[3];
    float mean = a * (1.f / 32768.f);
    float var = q * (1.f / 32768.f) - mean * mean;
    sh_mean = mean;
    sh_rstd = rsqrtf(var + GN_EPS);
  }
  __syncthreads();
  const float mean = sh_mean, rstd = sh_rstd;

  const int cl = t >> 3;                   // 0..31 channel within group
  const int cg = gg * 32 + cl;             // global channel
  const float wgt = nw[cg] * rstd;
  const float bia = nb[cg] - mean * wgt;
  const float* xrow = x + base + (size_t)cl * NS;
  ushort* dst = hnT + (size_t)b * NS * NC + cg;
  for (int k = 0; k < 32; ++k) {
    const int s = (t & 7) * 4 + k * 32;
    const float4 v = *(const float4*)(xrow + s);
    dst[(size_t)(s + 0) * NC] = f2bf(v.x * wgt + bia);
    dst[(size_t)(s + 1) * NC] = f2bf(v.y * wgt + bia);
    dst[(size_t)(s + 2) * NC] = f2bf(v.z * wgt + bia);
    dst[(size_t)(s + 3) * NC] = f2bf(v.w * wgt + bia);
  }
}

// ---------------------------------------------------------------------------
// Kernel 2/4: bf16 MFMA GEMM, 1D grid with bijective XCD-chunked swizzle.
// YDIM = o-tile count (6 for qkv, 2 for proj); grid = 8*YDIM*NB blocks.
// EPI=0: qkv epilogue (qT scaled by 0.125*log2e).  EPI=1: proj + residual.
// ---------------------------------------------------------------------------
template <int EPI, int YDIM>
__global__ __launch_bounds__(256) void mfma_gemm_kernel(
    const ushort* __restrict__ Wbf, const float* __restrict__ bias,
    const ushort* __restrict__ DATA, const float* __restrict__ X,
    ushort* __restrict__ qT, ushort* __restrict__ kT, ushort* __restrict__ vN,
    float* __restrict__ OUT) {
  __shared__ char smem[32768];
  char* T1 = smem;          // W-tile   [128 o][64 c] bf16, swizzled 128B rows
  char* T2 = smem + 16384;  // data-tile[128 s][64 c] bf16, swizzled
  // XCD-chunked bijective swizzle: grid = 8*YDIM*NB (divisible by 8 XCDs)
  const int nwg = 8 * YDIM * NB;
  const int o_id = blockIdx.x;
  const int wg = (o_id & 7) * (nwg >> 3) + (o_id >> 3);
  const int b = wg / (8 * YDIM);
  const int o0 = ((wg >> 3) % YDIM) * 128, s0 = (wg & 7) * 128;
  const int t = threadIdx.x, w = t >> 6, l = t & 63;
  const int g = l >> 4, li = l & 15;
  const ushort* wrow = Wbf + (size_t)o0 * NC;
  const ushort* drow = DATA + ((size_t)b * NS + s0) * NC;

  f32x4 acc[4][4];
  #pragma unroll
  for (int i = 0; i < 4; ++i)
    #pragma unroll
    for (int j = 0; j < 4; ++j) acc[i][j] = (f32x4){0.f, 0.f, 0.f, 0.f};

  const int oh = (w >> 1) * 64, sh = (w & 1) * 64;  // wave quadrant

  for (int k0 = 0; k0 < NC; k0 += 64) {
    short8 r1[4], r2[4];
    #pragma unroll
    for (int i = 0; i < 4; ++i) {
      const int id = t + 256 * i, row = id >> 3, ce = (id & 7) * 8;
      r1[i] = *(const short8*)(wrow + (size_t)row * NC + k0 + ce);
      r2[i] = *(const short8*)(drow + (size_t)row * NC + k0 + ce);
    }
    __syncthreads();
    #pragma unroll
    for (int i = 0; i < 4; ++i) {
      const int id = t + 256 * i, row = id >> 3, cb = (id & 7) * 16;
      const int dst = row * 128 + (cb ^ ((row & 7) << 4));
      *(short8*)(T1 + dst) = r1[i];
      *(short8*)(T2 + dst) = r2[i];
    }
    __syncthreads();
    __builtin_amdgcn_s_setprio(1);
    #pragma unroll
    for (int kk = 0; kk < 2; ++kk) {
      short8 af[4], bfr[4];
      #pragma unroll
      for (int ms = 0; ms < 4; ++ms) {
        const int row = oh + ms * 16 + li;
        af[ms] = *(const short8*)(T1 + row * 128 +
                                  ((kk * 64 + g * 16) ^ ((row & 7) << 4)));
      }
      #pragma unroll
      for (int ns = 0; ns < 4; ++ns) {
        const int row = sh + ns * 16 + li;
        bfr[ns] = *(const short8*)(T2 + row * 128 +
                                   ((kk * 64 + g * 16) ^ ((row & 7) << 4)));
      }
      #pragma unroll
      for (int ms = 0; ms < 4; ++ms)
        #pragma unroll
        for (int ns = 0; ns < 4; ++ns)
          acc[ms][ns] = __builtin_amdgcn_mfma_f32_16x16x32_bf16(
              af[ms], bfr[ns], acc[ms][ns], 0, 0, 0);
    }
    __builtin_amdgcn_s_setprio(0);
  }

  const int ob = o0 + oh;  // wave-uniform output-channel base
  if (EPI == 0) {
    const int tsr = ob >> 8;        // 0=q 1=k 2=v
    const int h = (ob >> 6) & 3;
    if (tsr < 2) {
      // q scale folds 1/sqrt(64) AND log2(e) so softmax uses exp2 directly
      const float sc = (tsr == 0) ? 0.18033688f : 1.0f;
      ushort* dst = (tsr == 0 ? qT : kT) + ((size_t)(b * 4 + h)) * NS * ND;
      #pragma unroll
      for (int ms = 0; ms < 4; ++ms) {
        const float4 bv = *(const float4*)(bias + ob + ms * 16 + g * 4);
        const int d0 = ms * 16 + g * 4;
        #pragma unroll
        for (int ns = 0; ns < 4; ++ns) {
          const int s = s0 + sh + ns * 16 + li;
          ushort4 pk;
          pk.x = f2bf((acc[ms][ns][0] + bv.x) * sc);
          pk.y = f2bf((acc[ms][ns][1] + bv.y) * sc);
          pk.z = f2bf((acc[ms][ns][2] + bv.z) * sc);
          pk.w = f2bf((acc[ms][ns][3] + bv.w) * sc);
          *(ushort4*)(dst + (size_t)s * ND + d0) = pk;
        }
      }
    } else {
      ushort* dst = vN + ((size_t)(b * 4 + h)) * ND * NS;
      #pragma unroll
      for (int ms = 0; ms < 4; ++ms) {
        const float4 bv = *(const float4*)(bias + ob + ms * 16 + g * 4);
        const float bvr[4] = {bv.x, bv.y, bv.z, bv.w};
        #pragma unroll
        for (int r = 0; r < 4; ++r) {
          const int d = ms * 16 + g * 4 + r;
          #pragma unroll
          for (int ns = 0; ns < 4; ++ns) {
            const int s = s0 + sh + ns * 16 + li;
            dst[(size_t)d * NS + s] = f2bf(acc[ms][ns][r] + bvr[r]);
          }
        }
      }
    }
  } else {
    float* outb = OUT + (size_t)b * NC * NS;
    const float* xb = X + (size_t)b * NC * NS;
    #pragma unroll
    for (int ms = 0; ms < 4; ++ms) {
      const float4 bv = *(const float4*)(bias + ob + ms * 16 + g * 4);
      const float bvr[4] = {bv.x, bv.y, bv.z, bv.w};
      #pragma unroll
      for (int r = 0; r < 4; ++r) {
        const int c = ob + ms * 16 + g * 4 + r;
        #pragma unroll
        for (int ns = 0; ns < 4; ++ns) {
          const int s = s0 + sh + ns * 16 + li;
          const size_t a = (size_t)c * NS + s;
          outb[a] = acc[ms][ns][r] + bvr[r] + xb[a];
        }
      }
    }
  }
}

// ---------------------------------------------------------------------------
// Kernel 3: MFMA flash attention (QBLK=128, KVBLK=64, fixed-max exp2 softmax,
// K/V double-buffer + async-STAGE). 1D grid (512) with XCD-chunked swizzle:
// each XCD gets 8 consecutive (b,h) groups -> K/V L2-resident (2 MB/XCD).
// ---------------------------------------------------------------------------
__global__ __launch_bounds__(256, 2) void attn_kernel(
    const ushort* __restrict__ qT, const ushort* __restrict__ kT,
    const ushort* __restrict__ vN, ushort* __restrict__ att2) {
  __shared__ char smem[49152];
  const int o_id = blockIdx.x;                 // 512 blocks
  const int wg = (o_id & 7) * 64 + (o_id >> 3);
  const int b = wg >> 5, h = (wg >> 3) & 3;
  const int sq0 = (wg & 7) * 128;
  const int t = threadIdx.x, w = t >> 6, l = t & 63;
  const int g = l >> 4, li = l & 15;
  char* Ps = smem + 32768 + w * 4096;  // per-wave [32 q][64 k] bf16, swizzled
  const size_t bh = (size_t)(b * 4 + h);
  const ushort* qbase = qT + bh * NS * ND + (size_t)sq0 * ND;
  const ushort* kbase = kT + bh * NS * ND;
  const ushort* vbase = vN + bh * ND * NS;

  // ---- stage Q (128 rows x 64 d) into the Ps region, hoist A-fragments ----
  #pragma unroll
  for (int i = 0; i < 4; ++i) {
    const int f = t + 256 * i;       // 0..1023 short8 chunks
    const int row = f >> 3, c8 = f & 7;
    short8 v = *(const short8*)(qbase + (size_t)row * ND + c8 * 8);
    *(short8*)(smem + 32768 + ((row * 128 + c8 * 16) ^ ((row & 7) << 4))) = v;
  }
  __syncthreads();
  short8 aq[2][2];
  #pragma unroll
  for (int m = 0; m < 2; ++m)
    #pragma unroll
    for (int kc = 0; kc < 2; ++kc) {
      const int row = w * 32 + m * 16 + li;
      aq[m][kc] = *(const short8*)(smem + 32768 +
          ((row * 128 + kc * 64 + g * 16) ^ ((row & 7) << 4)));
    }

  // ---- prologue: stage K/V tile 0 into buf0 ----
  const int srow = t >> 3, sc8 = t & 7;          // per thread: 2 short8/tile
  const int srow2 = (t + 256) >> 3, sc82 = (t + 256) & 7;
  {
    short8 k0a = *(const short8*)(kbase + (size_t)srow * ND + sc8 * 8);
    short8 k0b = *(const short8*)(kbase + (size_t)srow2 * ND + sc82 * 8);
    short8 v0a = *(const short8*)(vbase + (size_t)srow * NS + sc8 * 8);
    short8 v0b = *(const short8*)(vbase + (size_t)srow2 * NS + sc82 * 8);
    const int d1 = srow * 128 + ((sc8 * 16) ^ ((srow & 7) << 4));
    const int d2 = srow2 * 128 + ((sc82 * 16) ^ ((srow2 & 7) << 4));
    *(short8*)(smem + d1) = k0a;
    *(short8*)(smem + d2) = k0b;
    *(short8*)(smem + 8192 + d1) = v0a;
    *(short8*)(smem + 8192 + d2) = v0b;
  }

  f32x4 acc[2][4];
  #pragma unroll
  for (int m = 0; m < 2; ++m)
    #pragma unroll
    for (int dt = 0; dt < 4; ++dt) acc[m][dt] = (f32x4){0.f, 0.f, 0.f, 0.f};
  float lsum[2][4] = {};

  for (int kt = 0; kt < 16; ++kt) {
    __syncthreads();   // buf[kt&1] staged; previous tile's reads complete
    char* Kc = smem + (kt & 1) * 16384;
    char* Vc = Kc + 8192;

    // issue next tile's global loads (latency hidden under compute)
    short8 nk0, nk1, nv0, nv1;
    if (kt < 15) {
      const ushort* kb = kbase + (size_t)(kt + 1) * 64 * ND;
      const ushort* vb = vbase + (size_t)(kt + 1) * 64;
      nk0 = *(const short8*)(kb + (size_t)srow * ND + sc8 * 8);
      nk1 = *(const short8*)(kb + (size_t)srow2 * ND + sc82 * 8);
      nv0 = *(const short8*)(vb + (size_t)srow * NS + sc8 * 8);
      nv1 = *(const short8*)(vb + (size_t)srow2 * NS + sc82 * 8);
    }

    // ---- QK^T: 32q x 64k per wave ----
    f32x4 sv[2][4];
    __builtin_amdgcn_s_setprio(1);
    #pragma unroll
    for (int kst = 0; kst < 4; ++kst) {
      const int krow = kst * 16 + li;
      const int swz = (krow & 7) << 4;
      const short8 bk0 = *(const short8*)(Kc + ((krow * 128 + g * 16) ^ swz));
      const short8 bk1 = *(const short8*)(Kc + ((krow * 128 + 64 + g * 16) ^ swz));
      #pragma unroll
      for (int m = 0; m < 2; ++m) {
        f32x4 sa = {0.f, 0.f, 0.f, 0.f};
        sa = __builtin_amdgcn_mfma_f32_16x16x32_bf16(aq[m][0], bk0, sa, 0, 0, 0);
        sa = __builtin_amdgcn_mfma_f32_16x16x32_bf16(aq[m][1], bk1, sa, 0, 0, 0);
        sv[m][kst] = sa;
      }
    }
    __builtin_amdgcn_s_setprio(0);

    // ---- softmax: P = exp2(S) (scale pre-folded), partial l in-lane ----
    #pragma unroll
    for (int m = 0; m < 2; ++m)
      #pragma unroll
      for (int kst = 0; kst < 4; ++kst) {
        float p0 = __builtin_amdgcn_exp2f(sv[m][kst][0]);
        float p1 = __builtin_amdgcn_exp2f(sv[m][kst][1]);
        float p2 = __builtin_amdgcn_exp2f(sv[m][kst][2]);
        float p3 = __builtin_amdgcn_exp2f(sv[m][kst][3]);
        lsum[m][0] += p0; lsum[m][1] += p1;
        lsum[m][2] += p2; lsum[m][3] += p3;
        const int kcol = (kst * 16 + li) * 2;
        const int q0 = m * 16 + g * 4;
        *(ushort*)(Ps + ((q0 + 0) * 128 + (kcol ^ (((q0 + 0) & 7) << 4)))) = f2bf_fast(p0);
        *(ushort*)(Ps + ((q0 + 1) * 128 + (kcol ^ (((q0 + 1) & 7) << 4)))) = f2bf_fast(p1);
        *(ushort*)(Ps + ((q0 + 2) * 128 + (kcol ^ (((q0 + 2) & 7) << 4)))) = f2bf_fast(p2);
        *(ushort*)(Ps + ((q0 + 3) * 128 + (kcol ^ (((q0 + 3) & 7) << 4)))) = f2bf_fast(p3);
      }

    // ---- PV: acc[m][dt] += P[32q x 64k] * V[64k x 64d] ----
    __builtin_amdgcn_s_setprio(1);
    #pragma unroll
    for (int ks2 = 0; ks2 < 2; ++ks2) {
      short8 pa[2];
      #pragma unroll
      for (int m = 0; m < 2; ++m) {
        const int prow = m * 16 + li;
        pa[m] = *(const short8*)(Ps + (prow * 128 +
                 ((ks2 * 64 + g * 16) ^ ((li & 7) << 4))));
      }
      #pragma unroll
      for (int dt = 0; dt < 4; ++dt) {
        const int vrow = dt * 16 + li;
        const short8 bv = *(const short8*)(Vc + ((vrow * 128 + ks2 * 64 + g * 16)
                                                 ^ ((vrow & 7) << 4)));
        #pragma unroll
        for (int m = 0; m < 2; ++m)
          acc[m][dt] = __builtin_amdgcn_mfma_f32_16x16x32_bf16(
              pa[m], bv, acc[m][dt], 0, 0, 0);
      }
    }
    __builtin_amdgcn_s_setprio(0);

    // ---- write next tile to the other buffer ----
    if (kt < 15) {
      char* Kn = smem + ((kt + 1) & 1) * 16384;
      char* Vn = Kn + 8192;
      const int d1 = srow * 128 + ((sc8 * 16) ^ ((srow & 7) << 4));
      const int d2 = srow2 * 128 + ((sc82 * 16) ^ ((srow2 & 7) << 4));
      *(short8*)(Kn + d1) = nk0;
      *(short8*)(Kn + d2) = nk1;
      *(short8*)(Vn + d1) = nv0;
      *(short8*)(Vn + d2) = nv1;
    }
  }

  // ---- final l reduction (over the 16 li lanes) and output ----
  float linv[2][4];
  #pragma unroll
  for (int m = 0; m < 2; ++m)
    #pragma unroll
    for (int r = 0; r < 4; ++r) {
      float s = lsum[m][r];
      #pragma unroll
      for (int msk = 1; msk < 16; msk <<= 1) s += __shfl_xor(s, msk, 64);
      linv[m][r] = 1.f / s;
    }
  ushort* obase = att2 + ((size_t)b * NS + sq0 + w * 32) * NC + h * 64;
  #pragma unroll
  for (int m = 0; m < 2; ++m)
    #pragma unroll
    for (int dt = 0; dt < 4; ++dt)
      #pragma unroll
      for (int r = 0; r < 4; ++r)
        obase[(size_t)(m * 16 + g * 4 + r) * NC + dt * 16 + li] =
            f2bf(acc[m][dt][r] * linv[m][r]);
}

// ---------------------------------------------------------------------------
// ws (ushort): hnT[4.19M] qT[4.19M] kT[4.19M] vN[4.19M] att2[4.19M] wbf[262144]
// ---------------------------------------------------------------------------
extern "C" void kernel_launch(void* const* d_in, const int* in_sizes, int n_in,
                              void* d_out, int out_size, void* d_ws, size_t ws_size,
                              hipStream_t stream) {
  const float* x      = (const float*)d_in[0];
  const float* norm_w = (const float*)d_in[1];
  const float* norm_b = (const float*)d_in[2];
  const float* qkv_w  = (const float*)d_in[3];
  const float* qkv_b  = (const float*)d_in[4];
  const float* proj_w = (const float*)d_in[5];
  const float* proj_b = (const float*)d_in[6];
  float* out = (float*)d_out;

  ushort* hnT  = (ushort*)d_ws;
  ushort* qT   = hnT + (size_t)4194304;
  ushort* kT   = qT + (size_t)4194304;
  ushort* vN   = kT + (size_t)4194304;
  ushort* att2 = vN + (size_t)4194304;
  ushort* wbf  = att2 + (size_t)4194304;
  ushort* wq = wbf;
  ushort* wp = wbf + (size_t)196608;

  gn_wconv_kernel<<<dim3(384), 256, 0, stream>>>(
      x, norm_w, norm_b, hnT, qkv_w, proj_w, wbf);
  mfma_gemm_kernel<0, 6><<<dim3(768), 256, 0, stream>>>(
      wq, qkv_b, hnT, nullptr, qT, kT, vN, nullptr);
  attn_kernel<<<dim3(512), 256, 0, stream>>>(qT, kT, vN, att2);
  mfma_gemm_kernel<1, 2><<<dim3(256), 256, 0, stream>>>(
      wp, proj_b, att2, x, nullptr, nullptr, nullptr, out);
}

// Round 6
// 74.336 us; speedup vs baseline: 13.4892x; 1.1197x over previous
//
#include <hip/hip_runtime.h>

// AttentionBlock: B=16, C=256, H=W=32, NH=4, GROUPS=8
#define NB 16
#define NC 256
#define NS 1024   // H*W
#define NNH 4
#define ND 64     // C/NH
#define GN_EPS 1e-5f

typedef __attribute__((ext_vector_type(8))) short short8;   // 8 bf16 (4 VGPRs)
typedef __attribute__((ext_vector_type(4))) float f32x4;    // MFMA C/D

static __device__ __forceinline__ ushort f2bf(float x) {
  union { float f; unsigned u; } c; c.f = x;
  unsigned r = (c.u + 0x7fffu + ((c.u >> 16) & 1u)) >> 16;  // RNE
  return (ushort)r;
}
static __device__ __forceinline__ unsigned cvt_pk_bf16(float lo, float hi) {
  unsigned r;
  asm("v_cvt_pk_bf16_f32 %0, %1, %2" : "=v"(r) : "v"(lo), "v"(hi));
  return r;  // low16 = bf16(lo), high16 = bf16(hi)
}

// ---------------------------------------------------------------------------
// Kernel 1: fused GroupNorm (blocks 0..127) + weight bf16 convert (128..383).
// GN: one block per (b,g) -> hnT [b][s][c] bf16.
// ---------------------------------------------------------------------------
__global__ __launch_bounds__(256) void gn_wconv_kernel(
    const float* __restrict__ x, const float* __restrict__ nw,
    const float* __restrict__ nb, ushort* __restrict__ hnT,
    const float* __restrict__ qw, const float* __restrict__ pw,
    ushort* __restrict__ wbf) {
  const int bid = blockIdx.x;
  const int t = threadIdx.x;
  if (bid >= 128) {  // ---- weight convert: 65536 float4s over 256 blocks ----
    const int i = (bid - 128) * 256 + t;
    const float4 v = (i < 49152) ? *(const float4*)(qw + (size_t)i * 4)
                                 : *(const float4*)(pw + (size_t)(i - 49152) * 4);
    ushort4 u;
    u.x = f2bf(v.x); u.y = f2bf(v.y); u.z = f2bf(v.z); u.w = f2bf(v.w);
    *(ushort4*)(wbf + (size_t)i * 4) = u;
    return;
  }
  const int b = bid >> 3, gg = bid & 7;
  const size_t base = ((size_t)(b * NC + gg * 32)) * NS;  // 32768 floats
  const float4* xv = (const float4*)(x + base);

  float s1 = 0.f, s2 = 0.f;
  for (int i = t; i < 8192; i += 256) {
    float4 v = xv[i];
    s1 += v.x + v.y + v.z + v.w;
    s2 += v.x * v.x + v.y * v.y + v.z * v.z + v.w * v.w;
  }
  #pragma unroll
  for (int o = 32; o > 0; o >>= 1) {
    s1 += __shfl_down(s1, o, 64);
    s2 += __shfl_down(s2, o, 64);
  }
  __shared__ float rs1[4], rs2[4];
  __shared__ float sh_mean, sh_rstd;
  const int wid = t >> 6, lane = t & 63;
  if (lane == 0) { rs1[wid] = s1; rs2[wid] = s2; }
  __syncthreads();
  if (t == 0) {
    float a = rs1[0] + rs1[1] + rs1[2] + rs1[3];
    float q = rs2[0] + rs2[1] + rs2[2] + rs2[3];
    float mean = a * (1.f / 32768.f);
    float var = q * (1.f / 32768.f) - mean * mean;
    sh_mean = mean;
    sh_rstd = rsqrtf(var + GN_EPS);
  }
  __syncthreads();
  const float mean = sh_mean, rstd = sh_rstd;

  const int cl = t >> 3;                   // 0..31 channel within group
  const int cg = gg * 32 + cl;             // global channel
  const float wgt = nw[cg] * rstd;
  const float bia = nb[cg] - mean * wgt;
  const float* xrow = x + base + (size_t)cl * NS;
  ushort* dst = hnT + (size_t)b * NS * NC + cg;
  for (int k = 0; k < 32; ++k) {
    const int s = (t & 7) * 4 + k * 32;
    const float4 v = *(const float4*)(xrow + s);
    dst[(size_t)(s + 0) * NC] = f2bf(v.x * wgt + bia);
    dst[(size_t)(s + 1) * NC] = f2bf(v.y * wgt + bia);
    dst[(size_t)(s + 2) * NC] = f2bf(v.z * wgt + bia);
    dst[(size_t)(s + 3) * NC] = f2bf(v.w * wgt + bia);
  }
}

// ---------------------------------------------------------------------------
// Kernel 2/4: bf16 MFMA GEMM, 1D grid with bijective XCD-chunked swizzle.
// (unchanged from R4)
// ---------------------------------------------------------------------------
template <int EPI, int YDIM>
__global__ __launch_bounds__(256) void mfma_gemm_kernel(
    const ushort* __restrict__ Wbf, const float* __restrict__ bias,
    const ushort* __restrict__ DATA, const float* __restrict__ X,
    ushort* __restrict__ qT, ushort* __restrict__ kT, ushort* __restrict__ vN,
    float* __restrict__ OUT) {
  __shared__ char smem[32768];
  char* T1 = smem;          // W-tile   [128 o][64 c] bf16, swizzled 128B rows
  char* T2 = smem + 16384;  // data-tile[128 s][64 c] bf16, swizzled
  const int nwg = 8 * YDIM * NB;
  const int o_id = blockIdx.x;
  const int wg = (o_id & 7) * (nwg >> 3) + (o_id >> 3);
  const int b = wg / (8 * YDIM);
  const int o0 = ((wg >> 3) % YDIM) * 128, s0 = (wg & 7) * 128;
  const int t = threadIdx.x, w = t >> 6, l = t & 63;
  const int g = l >> 4, li = l & 15;
  const ushort* wrow = Wbf + (size_t)o0 * NC;
  const ushort* drow = DATA + ((size_t)b * NS + s0) * NC;

  f32x4 acc[4][4];
  #pragma unroll
  for (int i = 0; i < 4; ++i)
    #pragma unroll
    for (int j = 0; j < 4; ++j) acc[i][j] = (f32x4){0.f, 0.f, 0.f, 0.f};

  const int oh = (w >> 1) * 64, sh = (w & 1) * 64;  // wave quadrant

  for (int k0 = 0; k0 < NC; k0 += 64) {
    short8 r1[4], r2[4];
    #pragma unroll
    for (int i = 0; i < 4; ++i) {
      const int id = t + 256 * i, row = id >> 3, ce = (id & 7) * 8;
      r1[i] = *(const short8*)(wrow + (size_t)row * NC + k0 + ce);
      r2[i] = *(const short8*)(drow + (size_t)row * NC + k0 + ce);
    }
    __syncthreads();
    #pragma unroll
    for (int i = 0; i < 4; ++i) {
      const int id = t + 256 * i, row = id >> 3, cb = (id & 7) * 16;
      const int dst = row * 128 + (cb ^ ((row & 7) << 4));
      *(short8*)(T1 + dst) = r1[i];
      *(short8*)(T2 + dst) = r2[i];
    }
    __syncthreads();
    __builtin_amdgcn_s_setprio(1);
    #pragma unroll
    for (int kk = 0; kk < 2; ++kk) {
      short8 af[4], bfr[4];
      #pragma unroll
      for (int ms = 0; ms < 4; ++ms) {
        const int row = oh + ms * 16 + li;
        af[ms] = *(const short8*)(T1 + row * 128 +
                                  ((kk * 64 + g * 16) ^ ((row & 7) << 4)));
      }
      #pragma unroll
      for (int ns = 0; ns < 4; ++ns) {
        const int row = sh + ns * 16 + li;
        bfr[ns] = *(const short8*)(T2 + row * 128 +
                                   ((kk * 64 + g * 16) ^ ((row & 7) << 4)));
      }
      #pragma unroll
      for (int ms = 0; ms < 4; ++ms)
        #pragma unroll
        for (int ns = 0; ns < 4; ++ns)
          acc[ms][ns] = __builtin_amdgcn_mfma_f32_16x16x32_bf16(
              af[ms], bfr[ns], acc[ms][ns], 0, 0, 0);
    }
    __builtin_amdgcn_s_setprio(0);
  }

  const int ob = o0 + oh;  // wave-uniform output-channel base
  if (EPI == 0) {
    const int tsr = ob >> 8;        // 0=q 1=k 2=v
    const int h = (ob >> 6) & 3;
    if (tsr < 2) {
      // q scale folds 1/sqrt(64) AND log2(e) so softmax uses exp2 directly
      const float sc = (tsr == 0) ? 0.18033688f : 1.0f;
      ushort* dst = (tsr == 0 ? qT : kT) + ((size_t)(b * 4 + h)) * NS * ND;
      #pragma unroll
      for (int ms = 0; ms < 4; ++ms) {
        const float4 bv = *(const float4*)(bias + ob + ms * 16 + g * 4);
        const int d0 = ms * 16 + g * 4;
        #pragma unroll
        for (int ns = 0; ns < 4; ++ns) {
          const int s = s0 + sh + ns * 16 + li;
          ushort4 pk;
          pk.x = f2bf((acc[ms][ns][0] + bv.x) * sc);
          pk.y = f2bf((acc[ms][ns][1] + bv.y) * sc);
          pk.z = f2bf((acc[ms][ns][2] + bv.z) * sc);
          pk.w = f2bf((acc[ms][ns][3] + bv.w) * sc);
          *(ushort4*)(dst + (size_t)s * ND + d0) = pk;
        }
      }
    } else {
      ushort* dst = vN + ((size_t)(b * 4 + h)) * ND * NS;
      #pragma unroll
      for (int ms = 0; ms < 4; ++ms) {
        const float4 bv = *(const float4*)(bias + ob + ms * 16 + g * 4);
        const float bvr[4] = {bv.x, bv.y, bv.z, bv.w};
        #pragma unroll
        for (int r = 0; r < 4; ++r) {
          const int d = ms * 16 + g * 4 + r;
          #pragma unroll
          for (int ns = 0; ns < 4; ++ns) {
            const int s = s0 + sh + ns * 16 + li;
            dst[(size_t)d * NS + s] = f2bf(acc[ms][ns][r] + bvr[r]);
          }
        }
      }
    }
  } else {
    float* outb = OUT + (size_t)b * NC * NS;
    const float* xb = X + (size_t)b * NC * NS;
    #pragma unroll
    for (int ms = 0; ms < 4; ++ms) {
      const float4 bv = *(const float4*)(bias + ob + ms * 16 + g * 4);
      const float bvr[4] = {bv.x, bv.y, bv.z, bv.w};
      #pragma unroll
      for (int r = 0; r < 4; ++r) {
        const int c = ob + ms * 16 + g * 4 + r;
        #pragma unroll
        for (int ns = 0; ns < 4; ++ns) {
          const int s = s0 + sh + ns * 16 + li;
          const size_t a = (size_t)c * NS + s;
          outb[a] = acc[ms][ns][r] + bvr[r] + xb[a];
        }
      }
    }
  }
}

// ---------------------------------------------------------------------------
// Kernel 3: MFMA flash attention v4.
//  - 512 threads = 8 waves, QBLK=128 (16 q/wave), KVBLK=64 -> 4 waves/SIMD.
//  - SWAPPED QK^T: sT = mfma(K, Q) so each lane holds 4 consecutive keys of
//    one q row  (col=lane&15=q, row=4g+r=key; m89-verified C/D layout).
//    -> single lsum reg, cvt_pk packed P, 4x ds_write_b64 per kt (was 32 u16).
//  - fixed-max exp2 softmax, K/V dbuf + async-STAGE, XCD-chunked grid.
//  - LDS: KV dbuf 32KB + Ps 8x2KB = 48KB (Q staged in Ps region).
// ---------------------------------------------------------------------------
__global__ __launch_bounds__(512, 4) void attn_kernel(
    const ushort* __restrict__ qT, const ushort* __restrict__ kT,
    const ushort* __restrict__ vN, ushort* __restrict__ att2) {
  __shared__ char smem[49152];
  const int o_id = blockIdx.x;                 // 512 blocks
  const int wg = (o_id & 7) * 64 + (o_id >> 3);
  const int b = wg >> 5, h = (wg >> 3) & 3;
  const int sq0 = (wg & 7) * 128;
  const int t = threadIdx.x, w = t >> 6, l = t & 63;
  const int g = l >> 4, li = l & 15;
  const int sw = (li & 7) << 4;
  char* Ps = smem + 32768 + w * 2048;  // per-wave [16 q][64 k] bf16, swizzled
  const size_t bh = (size_t)(b * 4 + h);
  const ushort* qbase = qT + bh * NS * ND + (size_t)sq0 * ND;
  const ushort* kbase = kT + bh * NS * ND;
  const ushort* vbase = vN + bh * ND * NS;

  // ---- stage Q (128 rows x 64 d) into the Ps region, hoist B-fragments ----
  #pragma unroll
  for (int i = 0; i < 2; ++i) {
    const int f = t + 512 * i;       // 0..1023 short8 chunks
    const int row = f >> 3, c8 = f & 7;
    short8 v = *(const short8*)(qbase + (size_t)row * ND + c8 * 8);
    *(short8*)(smem + 32768 + ((row * 128 + c8 * 16) ^ ((row & 7) << 4))) = v;
  }
  __syncthreads();
  short8 aq0, aq1;
  {
    const int row = w * 16 + li;
    aq0 = *(const short8*)(smem + 32768 + row * 128 + ((g * 16) ^ sw));
    aq1 = *(const short8*)(smem + 32768 + row * 128 + ((64 + g * 16) ^ sw));
  }

  // ---- prologue: stage K/V tile 0 into buf0 (1 chunk each per thread) ----
  const int srow = t >> 3, sc8 = t & 7;   // 64 rows x 8 chunks = 512 threads
  const int sdst = srow * 128 + ((sc8 * 16) ^ ((srow & 7) << 4));
  {
    short8 k0 = *(const short8*)(kbase + (size_t)srow * ND + sc8 * 8);
    short8 v0 = *(const short8*)(vbase + (size_t)srow * NS + sc8 * 8);
    *(short8*)(smem + sdst) = k0;
    *(short8*)(smem + 8192 + sdst) = v0;
  }

  f32x4 acc[4];
  #pragma unroll
  for (int dt = 0; dt < 4; ++dt) acc[dt] = (f32x4){0.f, 0.f, 0.f, 0.f};
  float lsum = 0.f;

  for (int kt = 0; kt < 16; ++kt) {
    __syncthreads();   // buf[kt&1] staged; previous tile's reads complete
    char* Kc = smem + (kt & 1) * 16384;
    char* Vc = Kc + 8192;

    // issue next tile's global loads (latency hidden under compute)
    short8 nk, nv;
    if (kt < 15) {
      nk = *(const short8*)(kbase + (size_t)(kt + 1) * 64 * ND +
                            (size_t)srow * ND + sc8 * 8);
      nv = *(const short8*)(vbase + (size_t)srow * NS + (kt + 1) * 64 + sc8 * 8);
    }

    // ---- swapped QK^T + softmax, per 16-key subtile ----
    __builtin_amdgcn_s_setprio(1);
    #pragma unroll
    for (int kst = 0; kst < 4; ++kst) {
      const int krow = kst * 16 + li;
      const short8 bk0 = *(const short8*)(Kc + krow * 128 + ((g * 16) ^ sw));
      const short8 bk1 = *(const short8*)(Kc + krow * 128 + ((64 + g * 16) ^ sw));
      f32x4 sT = {0.f, 0.f, 0.f, 0.f};
      sT = __builtin_amdgcn_mfma_f32_16x16x32_bf16(bk0, aq0, sT, 0, 0, 0);
      sT = __builtin_amdgcn_mfma_f32_16x16x32_bf16(bk1, aq1, sT, 0, 0, 0);
      // lane holds S[q = sq0+w*16+li][key = kt*64+kst*16+4g+r], r=0..3
      const float p0 = __builtin_amdgcn_exp2f(sT[0]);
      const float p1 = __builtin_amdgcn_exp2f(sT[1]);
      const float p2 = __builtin_amdgcn_exp2f(sT[2]);
      const float p3 = __builtin_amdgcn_exp2f(sT[3]);
      lsum += (p0 + p1) + (p2 + p3);
      uint2 pk;
      pk.x = cvt_pk_bf16(p0, p1);
      pk.y = cvt_pk_bf16(p2, p3);
      *(uint2*)(Ps + li * 128 + ((kst * 32 + 8 * g) ^ sw)) = pk;
    }
    __builtin_amdgcn_s_setprio(0);

    // ---- PV: acc[dt] += P[16q x 64k] * V[64k x 64d] ----
    __builtin_amdgcn_s_setprio(1);
    #pragma unroll
    for (int ks2 = 0; ks2 < 2; ++ks2) {
      const short8 pa = *(const short8*)(Ps + li * 128 +
                                         ((ks2 * 64 + g * 16) ^ sw));
      #pragma unroll
      for (int dt = 0; dt < 4; ++dt) {
        const int vrow = dt * 16 + li;
        const short8 bv = *(const short8*)(Vc + vrow * 128 +
                                           ((ks2 * 64 + g * 16) ^ sw));
        acc[dt] = __builtin_amdgcn_mfma_f32_16x16x32_bf16(pa, bv, acc[dt], 0, 0, 0);
      }
    }
    __builtin_amdgcn_s_setprio(0);

    // ---- write next tile to the other buffer ----
    if (kt < 15) {
      char* Kn = smem + ((kt + 1) & 1) * 16384;
      *(short8*)(Kn + sdst) = nk;
      *(short8*)(Kn + 8192 + sdst) = nv;
    }
  }

  // ---- final l reduction (4 lanes share each q) and redistribution ----
  lsum += __shfl_xor(lsum, 16, 64);
  lsum += __shfl_xor(lsum, 32, 64);   // all lanes: l[q = w*16 + li]
  const float linv = 1.f / lsum;
  float lr[4];
  #pragma unroll
  for (int r = 0; r < 4; ++r) lr[r] = __shfl(linv, g * 4 + r, 64);

  // epilogue: out[b][s][c], c = h*64 + dt*16 + li, s = sq0 + w*16 + g*4 + r
  ushort* obase = att2 + ((size_t)b * NS + sq0 + w * 16) * NC + h * 64;
  #pragma unroll
  for (int dt = 0; dt < 4; ++dt)
    #pragma unroll
    for (int r = 0; r < 4; ++r)
      obase[(size_t)(g * 4 + r) * NC + dt * 16 + li] = f2bf(acc[dt][r] * lr[r]);
}

// ---------------------------------------------------------------------------
// ws (ushort): hnT[4.19M] qT[4.19M] kT[4.19M] vN[4.19M] att2[4.19M] wbf[262144]
// ---------------------------------------------------------------------------
extern "C" void kernel_launch(void* const* d_in, const int* in_sizes, int n_in,
                              void* d_out, int out_size, void* d_ws, size_t ws_size,
                              hipStream_t stream) {
  const float* x      = (const float*)d_in[0];
  const float* norm_w = (const float*)d_in[1];
  const float* norm_b = (const float*)d_in[2];
  const float* qkv_w  = (const float*)d_in[3];
  const float* qkv_b  = (const float*)d_in[4];
  const float* proj_w = (const float*)d_in[5];
  const float* proj_b = (const float*)d_in[6];
  float* out = (float*)d_out;

  ushort* hnT  = (ushort*)d_ws;
  ushort* qT   = hnT + (size_t)4194304;
  ushort* kT   = qT + (size_t)4194304;
  ushort* vN   = kT + (size_t)4194304;
  ushort* att2 = vN + (size_t)4194304;
  ushort* wbf  = att2 + (size_t)4194304;
  ushort* wq = wbf;
  ushort* wp = wbf + (size_t)196608;

  gn_wconv_kernel<<<dim3(384), 256, 0, stream>>>(
      x, norm_w, norm_b, hnT, qkv_w, proj_w, wbf);
  mfma_gemm_kernel<0, 6><<<dim3(768), 256, 0, stream>>>(
      wq, qkv_b, hnT, nullptr, qT, kT, vN, nullptr);
  attn_kernel<<<dim3(512), 512, 0, stream>>>(qT, kT, vN, att2);
  mfma_gemm_kernel<1, 2><<<dim3(256), 256, 0, stream>>>(
      wp, proj_b, att2, x, nullptr, nullptr, nullptr, out);
}

// Round 7
// 61.312 us; speedup vs baseline: 16.3546x; 1.2124x over previous
//
#include <hip/hip_runtime.h>

// AttentionBlock: B=16, C=256, H=W=32, NH=4, GROUPS=8
#define NB 16
#define NC 256
#define NS 1024   // H*W
#define NNH 4
#define ND 64     // C/NH
#define GN_EPS 1e-5f

typedef __attribute__((ext_vector_type(8))) short short8;   // 8 bf16 (4 VGPRs)
typedef __attribute__((ext_vector_type(4))) float f32x4;    // MFMA C/D

static __device__ __forceinline__ ushort f2bf(float x) {
  union { float f; unsigned u; } c; c.f = x;
  unsigned r = (c.u + 0x7fffu + ((c.u >> 16) & 1u)) >> 16;  // RNE
  return (ushort)r;
}
static __device__ __forceinline__ unsigned cvt_pk_bf16(float lo, float hi) {
  unsigned r;
  asm("v_cvt_pk_bf16_f32 %0, %1, %2" : "=v"(r) : "v"(lo), "v"(hi));
  return r;  // low16 = bf16(lo), high16 = bf16(hi)
}

// ---------------------------------------------------------------------------
// Kernel 1a: partial GN stats (blocks 0..1023) + weight bf16 conv (1024..1279).
// Stats: block (bg, part) reduces 4096 floats -> partials[bg*8+part] = {s1,s2}.
// ---------------------------------------------------------------------------
__global__ __launch_bounds__(256) void gnstat_wconv_kernel(
    const float* __restrict__ x, float2* __restrict__ partials,
    const float* __restrict__ qw, const float* __restrict__ pw,
    ushort* __restrict__ wbf) {
  const int bid = blockIdx.x;
  const int t = threadIdx.x;
  if (bid >= 1024) {  // ---- weight convert: 65536 float4s over 256 blocks ----
    const int i = (bid - 1024) * 256 + t;
    const float4 v = (i < 49152) ? *(const float4*)(qw + (size_t)i * 4)
                                 : *(const float4*)(pw + (size_t)(i - 49152) * 4);
    ushort4 u;
    u.x = f2bf(v.x); u.y = f2bf(v.y); u.z = f2bf(v.z); u.w = f2bf(v.w);
    *(ushort4*)(wbf + (size_t)i * 4) = u;
    return;
  }
  const int bg = bid >> 3, part = bid & 7;
  const float4* xv = (const float4*)(x + (size_t)bg * 32768 + part * 4096);
  float s1 = 0.f, s2 = 0.f;
  #pragma unroll
  for (int i = 0; i < 4; ++i) {
    float4 v = xv[t + 256 * i];
    s1 += v.x + v.y + v.z + v.w;
    s2 += v.x * v.x + v.y * v.y + v.z * v.z + v.w * v.w;
  }
  #pragma unroll
  for (int o = 32; o > 0; o >>= 1) {
    s1 += __shfl_down(s1, o, 64);
    s2 += __shfl_down(s2, o, 64);
  }
  __shared__ float rs1[4], rs2[4];
  const int wid = t >> 6;
  if ((t & 63) == 0) { rs1[wid] = s1; rs2[wid] = s2; }
  __syncthreads();
  if (t == 0) {
    partials[bg * 8 + part] = make_float2(rs1[0] + rs1[1] + rs1[2] + rs1[3],
                                          rs2[0] + rs2[1] + rs2[2] + rs2[3]);
  }
}

// ---------------------------------------------------------------------------
// Kernel 1b: GN apply. Block (bg, st): 32 channels x 128 s -> hnT [b][s][c]
// bf16, via LDS transpose tile (72B-stride rows, ushort4 coalesced stores).
// ---------------------------------------------------------------------------
__global__ __launch_bounds__(256) void gnapply_kernel(
    const float* __restrict__ x, const float* __restrict__ nw,
    const float* __restrict__ nb, const float2* __restrict__ partials,
    ushort* __restrict__ hnT) {
  const int bid = blockIdx.x;            // 1024
  const int bg = bid >> 3, st = bid & 7;
  const int b = bg >> 3, gg = bg & 7;
  const int t = threadIdx.x;

  float s1 = 0.f, s2 = 0.f;
  #pragma unroll
  for (int j = 0; j < 8; ++j) {
    const float2 p = partials[bg * 8 + j];
    s1 += p.x; s2 += p.y;
  }
  const float mean = s1 * (1.f / 32768.f);
  const float var = s2 * (1.f / 32768.f) - mean * mean;
  const float rstd = rsqrtf(var + GN_EPS);

  __shared__ ushort tile[128][36];  // 72B rows: 8B-aligned ushort4, low conflicts
  const int s4 = (t & 31) * 4;
  #pragma unroll
  for (int i = 0; i < 4; ++i) {
    const int c = (t >> 5) + 8 * i;
    const int cg = gg * 32 + c;
    const float wgt = nw[cg] * rstd;
    const float bia = nb[cg] - mean * wgt;
    const float4 v = *(const float4*)(x + ((size_t)(b * NC + cg)) * NS +
                                      st * 128 + s4);
    tile[s4 + 0][c] = f2bf(v.x * wgt + bia);
    tile[s4 + 1][c] = f2bf(v.y * wgt + bia);
    tile[s4 + 2][c] = f2bf(v.z * wgt + bia);
    tile[s4 + 3][c] = f2bf(v.w * wgt + bia);
  }
  __syncthreads();
  #pragma unroll
  for (int i = 0; i < 4; ++i) {
    const int idx = t + 256 * i;         // 128 rows x 8 chunks
    const int sr = idx >> 3, ch4 = (idx & 7) * 4;
    const ushort4 u = *(const ushort4*)&tile[sr][ch4];
    *(ushort4*)(hnT + ((size_t)(b * NS + st * 128 + sr)) * NC + gg * 32 + ch4) = u;
  }
}

// ---------------------------------------------------------------------------
// Kernel 2/4: bf16 MFMA GEMM, 1D grid with bijective XCD-chunked swizzle.
// (unchanged from R4/R5)
// ---------------------------------------------------------------------------
template <int EPI, int YDIM>
__global__ __launch_bounds__(256) void mfma_gemm_kernel(
    const ushort* __restrict__ Wbf, const float* __restrict__ bias,
    const ushort* __restrict__ DATA, const float* __restrict__ X,
    ushort* __restrict__ qT, ushort* __restrict__ kT, ushort* __restrict__ vN,
    float* __restrict__ OUT) {
  __shared__ char smem[32768];
  char* T1 = smem;          // W-tile   [128 o][64 c] bf16, swizzled 128B rows
  char* T2 = smem + 16384;  // data-tile[128 s][64 c] bf16, swizzled
  const int nwg = 8 * YDIM * NB;
  const int o_id = blockIdx.x;
  const int wg = (o_id & 7) * (nwg >> 3) + (o_id >> 3);
  const int b = wg / (8 * YDIM);
  const int o0 = ((wg >> 3) % YDIM) * 128, s0 = (wg & 7) * 128;
  const int t = threadIdx.x, w = t >> 6, l = t & 63;
  const int g = l >> 4, li = l & 15;
  const ushort* wrow = Wbf + (size_t)o0 * NC;
  const ushort* drow = DATA + ((size_t)b * NS + s0) * NC;

  f32x4 acc[4][4];
  #pragma unroll
  for (int i = 0; i < 4; ++i)
    #pragma unroll
    for (int j = 0; j < 4; ++j) acc[i][j] = (f32x4){0.f, 0.f, 0.f, 0.f};

  const int oh = (w >> 1) * 64, sh = (w & 1) * 64;  // wave quadrant

  for (int k0 = 0; k0 < NC; k0 += 64) {
    short8 r1[4], r2[4];
    #pragma unroll
    for (int i = 0; i < 4; ++i) {
      const int id = t + 256 * i, row = id >> 3, ce = (id & 7) * 8;
      r1[i] = *(const short8*)(wrow + (size_t)row * NC + k0 + ce);
      r2[i] = *(const short8*)(drow + (size_t)row * NC + k0 + ce);
    }
    __syncthreads();
    #pragma unroll
    for (int i = 0; i < 4; ++i) {
      const int id = t + 256 * i, row = id >> 3, cb = (id & 7) * 16;
      const int dst = row * 128 + (cb ^ ((row & 7) << 4));
      *(short8*)(T1 + dst) = r1[i];
      *(short8*)(T2 + dst) = r2[i];
    }
    __syncthreads();
    __builtin_amdgcn_s_setprio(1);
    #pragma unroll
    for (int kk = 0; kk < 2; ++kk) {
      short8 af[4], bfr[4];
      #pragma unroll
      for (int ms = 0; ms < 4; ++ms) {
        const int row = oh + ms * 16 + li;
        af[ms] = *(const short8*)(T1 + row * 128 +
                                  ((kk * 64 + g * 16) ^ ((row & 7) << 4)));
      }
      #pragma unroll
      for (int ns = 0; ns < 4; ++ns) {
        const int row = sh + ns * 16 + li;
        bfr[ns] = *(const short8*)(T2 + row * 128 +
                                   ((kk * 64 + g * 16) ^ ((row & 7) << 4)));
      }
      #pragma unroll
      for (int ms = 0; ms < 4; ++ms)
        #pragma unroll
        for (int ns = 0; ns < 4; ++ns)
          acc[ms][ns] = __builtin_amdgcn_mfma_f32_16x16x32_bf16(
              af[ms], bfr[ns], acc[ms][ns], 0, 0, 0);
    }
    __builtin_amdgcn_s_setprio(0);
  }

  const int ob = o0 + oh;  // wave-uniform output-channel base
  if (EPI == 0) {
    const int tsr = ob >> 8;        // 0=q 1=k 2=v
    const int h = (ob >> 6) & 3;
    if (tsr < 2) {
      // q scale folds 1/sqrt(64) AND log2(e) so softmax uses exp2 directly
      const float sc = (tsr == 0) ? 0.18033688f : 1.0f;
      ushort* dst = (tsr == 0 ? qT : kT) + ((size_t)(b * 4 + h)) * NS * ND;
      #pragma unroll
      for (int ms = 0; ms < 4; ++ms) {
        const float4 bv = *(const float4*)(bias + ob + ms * 16 + g * 4);
        const int d0 = ms * 16 + g * 4;
        #pragma unroll
        for (int ns = 0; ns < 4; ++ns) {
          const int s = s0 + sh + ns * 16 + li;
          ushort4 pk;
          pk.x = f2bf((acc[ms][ns][0] + bv.x) * sc);
          pk.y = f2bf((acc[ms][ns][1] + bv.y) * sc);
          pk.z = f2bf((acc[ms][ns][2] + bv.z) * sc);
          pk.w = f2bf((acc[ms][ns][3] + bv.w) * sc);
          *(ushort4*)(dst + (size_t)s * ND + d0) = pk;
        }
      }
    } else {
      ushort* dst = vN + ((size_t)(b * 4 + h)) * ND * NS;
      #pragma unroll
      for (int ms = 0; ms < 4; ++ms) {
        const float4 bv = *(const float4*)(bias + ob + ms * 16 + g * 4);
        const float bvr[4] = {bv.x, bv.y, bv.z, bv.w};
        #pragma unroll
        for (int r = 0; r < 4; ++r) {
          const int d = ms * 16 + g * 4 + r;
          #pragma unroll
          for (int ns = 0; ns < 4; ++ns) {
            const int s = s0 + sh + ns * 16 + li;
            dst[(size_t)d * NS + s] = f2bf(acc[ms][ns][r] + bvr[r]);
          }
        }
      }
    }
  } else {
    float* outb = OUT + (size_t)b * NC * NS;
    const float* xb = X + (size_t)b * NC * NS;
    #pragma unroll
    for (int ms = 0; ms < 4; ++ms) {
      const float4 bv = *(const float4*)(bias + ob + ms * 16 + g * 4);
      const float bvr[4] = {bv.x, bv.y, bv.z, bv.w};
      #pragma unroll
      for (int r = 0; r < 4; ++r) {
        const int c = ob + ms * 16 + g * 4 + r;
        #pragma unroll
        for (int ns = 0; ns < 4; ++ns) {
          const int s = s0 + sh + ns * 16 + li;
          const size_t a = (size_t)c * NS + s;
          outb[a] = acc[ms][ns][r] + bvr[r] + xb[a];
        }
      }
    }
  }
}

// ---------------------------------------------------------------------------
// Kernel 3: MFMA flash attention v5.
//  - 512 threads = 8 waves, QBLK=256 (32 q/wave, m=0,1), KVBLK=64, grid 256.
//  - Doubles fragment reuse vs v4: 20 ds_read_b128 per 32 MFMA per kt
//    (was 18 per 16) -> halves LDS bytes/MFMA (the binding resource).
//  - Swapped QK^T (lane holds 4 consecutive keys of one q row), fixed-max
//    exp2 softmax, cvt_pk P-pack, K/V dbuf + async-STAGE, XCD-chunked grid.
//  - LDS 64KB: [0,32K) K/V dbuf, [32K,64K) Q-stage then per-wave Ps (4KB).
// ---------------------------------------------------------------------------
__global__ __launch_bounds__(512, 2) void attn_kernel(
    const ushort* __restrict__ qT, const ushort* __restrict__ kT,
    const ushort* __restrict__ vN, ushort* __restrict__ att2) {
  __shared__ char smem[65536];
  const int o_id = blockIdx.x;                 // 256 blocks
  const int wg = (o_id & 7) * 32 + (o_id >> 3);
  const int b = wg >> 4, h = (wg >> 2) & 3;
  const int sq0 = (wg & 3) * 256;
  const int t = threadIdx.x, w = t >> 6, l = t & 63;
  const int g = l >> 4, li = l & 15;
  const int sw = (li & 7) << 4;
  char* Ps = smem + 32768 + w * 4096;  // per-wave [32 q][64 k] bf16, swizzled
  const size_t bh = (size_t)(b * 4 + h);
  const ushort* qbase = qT + bh * NS * ND + (size_t)sq0 * ND;
  const ushort* kbase = kT + bh * NS * ND;
  const ushort* vbase = vN + bh * ND * NS;

  // ---- stage Q (256 rows x 64 d) into [32K,64K), hoist B-fragments ----
  #pragma unroll
  for (int i = 0; i < 4; ++i) {
    const int f = t + 512 * i;       // 0..2047 short8 chunks
    const int row = f >> 3, c8 = f & 7;
    short8 v = *(const short8*)(qbase + (size_t)row * ND + c8 * 8);
    *(short8*)(smem + 32768 + ((row * 128 + c8 * 16) ^ ((row & 7) << 4))) = v;
  }
  __syncthreads();
  short8 aq[2][2];
  #pragma unroll
  for (int m = 0; m < 2; ++m) {
    const int row = w * 32 + m * 16 + li;   // row&7 == li&7
    aq[m][0] = *(const short8*)(smem + 32768 + row * 128 + ((g * 16) ^ sw));
    aq[m][1] = *(const short8*)(smem + 32768 + row * 128 + ((64 + g * 16) ^ sw));
  }

  // ---- prologue: stage K/V tile 0 into buf0 (1 chunk each per thread) ----
  const int srow = t >> 3, sc8 = t & 7;   // 64 rows x 8 chunks = 512 threads
  const int sdst = srow * 128 + ((sc8 * 16) ^ ((srow & 7) << 4));
  {
    short8 k0 = *(const short8*)(kbase + (size_t)srow * ND + sc8 * 8);
    short8 v0 = *(const short8*)(vbase + (size_t)srow * NS + sc8 * 8);
    *(short8*)(smem + sdst) = k0;
    *(short8*)(smem + 8192 + sdst) = v0;
  }

  f32x4 acc[2][4];
  #pragma unroll
  for (int m = 0; m < 2; ++m)
    #pragma unroll
    for (int dt = 0; dt < 4; ++dt) acc[m][dt] = (f32x4){0.f, 0.f, 0.f, 0.f};
  float lsum[2] = {0.f, 0.f};

  for (int kt = 0; kt < 16; ++kt) {
    __syncthreads();   // buf[kt&1] staged; previous tile's reads complete
    char* Kc = smem + (kt & 1) * 16384;
    char* Vc = Kc + 8192;

    // issue next tile's global loads (latency hidden under compute)
    short8 nk, nv;
    if (kt < 15) {
      nk = *(const short8*)(kbase + (size_t)(kt + 1) * 64 * ND +
                            (size_t)srow * ND + sc8 * 8);
      nv = *(const short8*)(vbase + (size_t)srow * NS + (kt + 1) * 64 + sc8 * 8);
    }

    // ---- swapped QK^T + softmax, per 16-key subtile x 2 q-halves ----
    __builtin_amdgcn_s_setprio(1);
    #pragma unroll
    for (int kst = 0; kst < 4; ++kst) {
      const int krow = kst * 16 + li;
      const short8 bk0 = *(const short8*)(Kc + krow * 128 + ((g * 16) ^ sw));
      const short8 bk1 = *(const short8*)(Kc + krow * 128 + ((64 + g * 16) ^ sw));
      #pragma unroll
      for (int m = 0; m < 2; ++m) {
        f32x4 sT = {0.f, 0.f, 0.f, 0.f};
        sT = __builtin_amdgcn_mfma_f32_16x16x32_bf16(bk0, aq[m][0], sT, 0, 0, 0);
        sT = __builtin_amdgcn_mfma_f32_16x16x32_bf16(bk1, aq[m][1], sT, 0, 0, 0);
        // lane holds S[q = sq0+w*32+m*16+li][key = kt*64+kst*16+4g+r]
        const float p0 = __builtin_amdgcn_exp2f(sT[0]);
        const float p1 = __builtin_amdgcn_exp2f(sT[1]);
        const float p2 = __builtin_amdgcn_exp2f(sT[2]);
        const float p3 = __builtin_amdgcn_exp2f(sT[3]);
        lsum[m] += (p0 + p1) + (p2 + p3);
        uint2 pk;
        pk.x = cvt_pk_bf16(p0, p1);
        pk.y = cvt_pk_bf16(p2, p3);
        *(uint2*)(Ps + (m * 16 + li) * 128 + ((kst * 32 + 8 * g) ^ sw)) = pk;
      }
    }
    __builtin_amdgcn_s_setprio(0);

    // ---- PV: acc[m][dt] += P[32q x 64k] * V[64k x 64d] ----
    __builtin_amdgcn_s_setprio(1);
    #pragma unroll
    for (int ks2 = 0; ks2 < 2; ++ks2) {
      short8 pa[2];
      #pragma unroll
      for (int m = 0; m < 2; ++m)
        pa[m] = *(const short8*)(Ps + (m * 16 + li) * 128 +
                                 ((ks2 * 64 + g * 16) ^ sw));
      #pragma unroll
      for (int dt = 0; dt < 4; ++dt) {
        const int vrow = dt * 16 + li;
        const short8 bv = *(const short8*)(Vc + vrow * 128 +
                                           ((ks2 * 64 + g * 16) ^ sw));
        #pragma unroll
        for (int m = 0; m < 2; ++m)
          acc[m][dt] = __builtin_amdgcn_mfma_f32_16x16x32_bf16(
              pa[m], bv, acc[m][dt], 0, 0, 0);
      }
    }
    __builtin_amdgcn_s_setprio(0);

    // ---- write next tile to the other buffer ----
    if (kt < 15) {
      char* Kn = smem + ((kt + 1) & 1) * 16384;
      *(short8*)(Kn + sdst) = nk;
      *(short8*)(Kn + 8192 + sdst) = nv;
    }
  }

  // ---- final l reduction (4 g-lanes share each q) and redistribution ----
  float lr[2][4];
  #pragma unroll
  for (int m = 0; m < 2; ++m) {
    float s = lsum[m];
    s += __shfl_xor(s, 16, 64);
    s += __shfl_xor(s, 32, 64);     // all lanes: l[q = w*32 + m*16 + li]
    const float linv = 1.f / s;
    #pragma unroll
    for (int r = 0; r < 4; ++r) lr[m][r] = __shfl(linv, g * 4 + r, 64);
  }

  // epilogue: out[b][s][c], c = h*64 + dt*16 + li, s = sq0+w*32+m*16+g*4+r
  ushort* obase = att2 + ((size_t)b * NS + sq0 + w * 32) * NC + h * 64;
  #pragma unroll
  for (int m = 0; m < 2; ++m)
    #pragma unroll
    for (int dt = 0; dt < 4; ++dt)
      #pragma unroll
      for (int r = 0; r < 4; ++r)
        obase[(size_t)(m * 16 + g * 4 + r) * NC + dt * 16 + li] =
            f2bf(acc[m][dt][r] * lr[m][r]);
}

// ---------------------------------------------------------------------------
// ws (ushort): hnT[4.19M] qT[4.19M] kT[4.19M] vN[4.19M] att2[4.19M]
//              wbf[262144] partials[f2 x 1024]
// ---------------------------------------------------------------------------
extern "C" void kernel_launch(void* const* d_in, const int* in_sizes, int n_in,
                              void* d_out, int out_size, void* d_ws, size_t ws_size,
                              hipStream_t stream) {
  const float* x      = (const float*)d_in[0];
  const float* norm_w = (const float*)d_in[1];
  const float* norm_b = (const float*)d_in[2];
  const float* qkv_w  = (const float*)d_in[3];
  const float* qkv_b  = (const float*)d_in[4];
  const float* proj_w = (const float*)d_in[5];
  const float* proj_b = (const float*)d_in[6];
  float* out = (float*)d_out;

  ushort* hnT  = (ushort*)d_ws;
  ushort* qT   = hnT + (size_t)4194304;
  ushort* kT   = qT + (size_t)4194304;
  ushort* vN   = kT + (size_t)4194304;
  ushort* att2 = vN + (size_t)4194304;
  ushort* wbf  = att2 + (size_t)4194304;
  float2* partials = (float2*)(wbf + (size_t)262144);
  ushort* wq = wbf;
  ushort* wp = wbf + (size_t)196608;

  gnstat_wconv_kernel<<<dim3(1280), 256, 0, stream>>>(
      x, partials, qkv_w, proj_w, wbf);
  gnapply_kernel<<<dim3(1024), 256, 0, stream>>>(
      x, norm_w, norm_b, partials, hnT);
  mfma_gemm_kernel<0, 6><<<dim3(768), 256, 0, stream>>>(
      wq, qkv_b, hnT, nullptr, qT, kT, vN, nullptr);
  attn_kernel<<<dim3(256), 512, 0, stream>>>(qT, kT, vN, att2);
  mfma_gemm_kernel<1, 2><<<dim3(256), 256, 0, stream>>>(
      wp, proj_b, att2, x, nullptr, nullptr, nullptr, out);
}